// Round 1
// baseline (1890.496 us; speedup 1.0000x reference)
//
#include <hip/hip_runtime.h>
#include <math.h>

#define NPIX 2304   // 48*48
#define NCH  512
#define NB   8
#define KNUM 230    // int(2304*0.1)

// ---------------- reduction helpers ----------------
__device__ __forceinline__ float waveSum(float v) {
    #pragma unroll
    for (int o = 32; o > 0; o >>= 1) v += __shfl_down(v, o);
    return v;
}
__device__ __forceinline__ float waveMax(float v) {
    #pragma unroll
    for (int o = 32; o > 0; o >>= 1) v = fmaxf(v, __shfl_down(v, o));
    return v;
}
__device__ __forceinline__ int waveSumI(int v) {
    #pragma unroll
    for (int o = 32; o > 0; o >>= 1) v += __shfl_down(v, o);
    return v;
}
// 256-thread block reductions (4 waves). Leading sync protects scratch reuse.
__device__ __forceinline__ float blockSum256(float v, float* sc4) {
    v = waveSum(v);
    __syncthreads();
    if ((threadIdx.x & 63) == 0) sc4[threadIdx.x >> 6] = v;
    __syncthreads();
    return sc4[0] + sc4[1] + sc4[2] + sc4[3];
}
__device__ __forceinline__ float blockMax256(float v, float* sc4) {
    v = waveMax(v);
    __syncthreads();
    if ((threadIdx.x & 63) == 0) sc4[threadIdx.x >> 6] = v;
    __syncthreads();
    return fmaxf(fmaxf(sc4[0], sc4[1]), fmaxf(sc4[2], sc4[3]));
}
__device__ __forceinline__ int blockSumI256(int v, int* sc4) {
    v = waveSumI(v);
    __syncthreads();
    if ((threadIdx.x & 63) == 0) sc4[threadIdx.x >> 6] = v;
    __syncthreads();
    return sc4[0] + sc4[1] + sc4[2] + sc4[3];
}

// ---------------- generic tiled fp32 GEMM ----------------
// out[b,m,n] = act( alpha*scale[m] * sum_k A[m,k]*in[b,k,n] + bias[m] + zb[b,m] )
// AK=true: A stored K-major, A[k,m] at Amat[k*lda+m] (used for attention q^T).
// If in1 != null, k>=512 reads come from in1 (channel-concat input).
template<bool AK>
__global__ __launch_bounds__(256) void gemm_k(
    const float* __restrict__ Amat, int lda,
    const float* __restrict__ in0, size_t in0BStride,
    const float* __restrict__ in1, size_t in1BStride,
    float* __restrict__ outp, size_t outBStride,
    const float* __restrict__ scale, const float* __restrict__ bias,
    const float* __restrict__ zb,
    int M, int K, int act, float alpha)
{
    __shared__ float As[16][64];
    __shared__ float Bs[16][64];
    const int b  = blockIdx.z;
    const int n0 = blockIdx.x * 64;
    const int m0 = blockIdx.y * 64;
    const int t  = threadIdx.x;
    const int tm = (t >> 4) << 2;
    const int tn = (t & 15) << 2;
    float acc[4][4] = {};

    for (int k0 = 0; k0 < K; k0 += 16) {
        if (AK) {
            const int k = t >> 4;
            const int m = (t & 15) << 2;
            float4 v = *reinterpret_cast<const float4*>(Amat + (size_t)(k0 + k) * lda + (m0 + m));
            *reinterpret_cast<float4*>(&As[k][m]) = v;
        } else {
            const int m = t >> 2;
            const int k = (t & 3) << 2;
            float4 v = *reinterpret_cast<const float4*>(Amat + (size_t)(m0 + m) * lda + (k0 + k));
            As[k][m]   = v.x; As[k+1][m] = v.y; As[k+2][m] = v.z; As[k+3][m] = v.w;
        }
        {
            const int k = t >> 4;
            const int n = (t & 15) << 2;
            const float* src; int krel;
            if (in1 != nullptr && (k0 + k) >= NCH) { src = in1 + (size_t)b * in1BStride; krel = k0 + k - NCH; }
            else                                   { src = in0 + (size_t)b * in0BStride; krel = k0 + k; }
            float4 v = *reinterpret_cast<const float4*>(src + (size_t)krel * NPIX + (n0 + n));
            *reinterpret_cast<float4*>(&Bs[k][n]) = v;
        }
        __syncthreads();
        #pragma unroll
        for (int kk = 0; kk < 16; ++kk) {
            const float4 av = *reinterpret_cast<const float4*>(&As[kk][tm]);
            const float4 bv = *reinterpret_cast<const float4*>(&Bs[kk][tn]);
            float a[4]  = {av.x, av.y, av.z, av.w};
            float bb[4] = {bv.x, bv.y, bv.z, bv.w};
            #pragma unroll
            for (int i = 0; i < 4; ++i)
                #pragma unroll
                for (int j = 0; j < 4; ++j)
                    acc[i][j] = fmaf(a[i], bb[j], acc[i][j]);
        }
        __syncthreads();
    }
    #pragma unroll
    for (int i = 0; i < 4; ++i) {
        const int m = m0 + tm + i;
        float sc = alpha;
        if (scale) sc *= scale[m];
        float bi = 0.f;
        if (bias) bi += bias[m];
        if (zb)   bi += zb[(size_t)b * M + m];
        float vals[4];
        #pragma unroll
        for (int j = 0; j < 4; ++j) {
            float v = fmaf(acc[i][j], sc, bi);
            if (act == 1) v = fmaxf(v, 0.f);
            vals[j] = v;
        }
        float* op = outp + (size_t)b * outBStride + (size_t)m * NPIX + (n0 + tn);
        *reinterpret_cast<float4*>(op) = make_float4(vals[0], vals[1], vals[2], vals[3]);
    }
}

// ---------------- depthwise 3x3 + BN + ReLU ----------------
__global__ __launch_bounds__(256) void dwconv_bn_relu(
    const float* __restrict__ in, const float* __restrict__ w,
    const float* __restrict__ g, const float* __restrict__ bb,
    float* __restrict__ outp)
{
    const int idx = blockIdx.x * 256 + threadIdx.x;      // exactly B*C*N threads
    const int n = idx % NPIX;
    const int c = (idx / NPIX) % NCH;
    const int b = idx / (NPIX * NCH);
    const int y = n / 48, x = n % 48;
    const float* base = in + ((size_t)(b * NCH + c)) * NPIX;
    const float* wc = w + c * 9;
    float s = 0.f;
    #pragma unroll
    for (int dy = -1; dy <= 1; ++dy) {
        const int yy = y + dy;
        if (yy < 0 || yy >= 48) continue;
        #pragma unroll
        for (int dx = -1; dx <= 1; ++dx) {
            const int xx = x + dx;
            if (xx < 0 || xx >= 48) continue;
            s = fmaf(base[yy * 48 + xx], wc[(dy + 1) * 3 + (dx + 1)], s);
        }
    }
    const float invs = 1.0f / sqrtf(1.0f + 1e-5f);
    const float v = fmaf(s, g[c] * invs, bb[c]);
    outp[idx] = fmaxf(v, 0.f);
}

// ---------------- ContextBlock: mask logits / softmax / pooling ----------------
__global__ __launch_bounds__(256) void mask_logits(
    const float* __restrict__ x, const float* __restrict__ cmw,
    const float* __restrict__ cmb, float* __restrict__ logits)
{
    const int idx = blockIdx.x * 256 + threadIdx.x;      // B*N threads
    const int n = idx % NPIX, b = idx / NPIX;
    const float* xb = x + (size_t)b * NCH * NPIX + n;
    float s = cmb[0];
    for (int c = 0; c < NCH; ++c) s = fmaf(xb[(size_t)c * NPIX], cmw[c], s);
    logits[idx] = s;
}

__global__ __launch_bounds__(256) void softmax_mask(
    const float* __restrict__ logits, float* __restrict__ mask)
{
    __shared__ float sc[4];
    const int b = blockIdx.x, t = threadIdx.x;
    const float* lr = logits + (size_t)b * NPIX;
    float mx = -3.4e38f;
    for (int i = t; i < NPIX; i += 256) mx = fmaxf(mx, lr[i]);
    mx = blockMax256(mx, sc);
    float s = 0.f;
    for (int i = t; i < NPIX; i += 256) s += expf(lr[i] - mx);
    s = blockSum256(s, sc);
    const float inv = 1.0f / s;
    for (int i = t; i < NPIX; i += 256) mask[(size_t)b * NPIX + i] = expf(lr[i] - mx) * inv;
}

__global__ __launch_bounds__(256) void ctx_pool(
    const float* __restrict__ x, const float* __restrict__ mask, float* __restrict__ ctx)
{
    const int lane = threadIdx.x & 63, w = threadIdx.x >> 6;
    const int c = blockIdx.x * 4 + w;
    const int b = blockIdx.y;
    const float* xr = x + ((size_t)(b * NCH + c)) * NPIX;
    const float* mr = mask + (size_t)b * NPIX;
    float s = 0.f;
    for (int i = lane; i < NPIX; i += 64) s = fmaf(xr[i], mr[i], s);
    s = waveSum(s);
    if (lane == 0) ctx[b * NCH + c] = s;
}

// ---------------- channel MLPs (channel_add + channel_mul) ----------------
__global__ __launch_bounds__(128) void chan_mlps(
    const float* __restrict__ ctxv,
    const float* __restrict__ mw1, const float* __restrict__ mb1,
    const float* __restrict__ mlg, const float* __restrict__ mlb,
    const float* __restrict__ mw2, const float* __restrict__ mb2,
    const float* __restrict__ aw1, const float* __restrict__ ab1,
    const float* __restrict__ alg, const float* __restrict__ alb,
    const float* __restrict__ aw2, const float* __restrict__ ab2,
    float* __restrict__ mulo, float* __restrict__ addo)
{
    __shared__ float cs[512];
    __shared__ float hm[128], ha[128];
    __shared__ float sc[2];
    const int b = blockIdx.x, t = threadIdx.x;
    for (int i = t; i < 512; i += 128) cs[i] = ctxv[b * 512 + i];
    __syncthreads();
    float hmv = mb1[t], hav = ab1[t];
    for (int c = 0; c < 512; ++c) {
        const float cv = cs[c];
        hmv = fmaf(cv, mw1[t * 512 + c], hmv);
        hav = fmaf(cv, aw1[t * 512 + c], hav);
    }
    // LayerNorm(mul path) over 128 + ReLU
    {
        float s1 = waveSum(hmv);
        __syncthreads();
        if ((t & 63) == 0) sc[t >> 6] = s1;
        __syncthreads();
        const float mu = (sc[0] + sc[1]) * (1.0f / 128.0f);
        const float d = hmv - mu;
        float s2 = waveSum(d * d);
        __syncthreads();
        if ((t & 63) == 0) sc[t >> 6] = s2;
        __syncthreads();
        const float var = (sc[0] + sc[1]) * (1.0f / 128.0f);
        hm[t] = fmaxf(d / sqrtf(var + 1e-5f) * mlg[t] + mlb[t], 0.f);
    }
    // LayerNorm(add path) over 128 + ReLU
    {
        float s1 = waveSum(hav);
        __syncthreads();
        if ((t & 63) == 0) sc[t >> 6] = s1;
        __syncthreads();
        const float mu = (sc[0] + sc[1]) * (1.0f / 128.0f);
        const float d = hav - mu;
        float s2 = waveSum(d * d);
        __syncthreads();
        if ((t & 63) == 0) sc[t >> 6] = s2;
        __syncthreads();
        const float var = (sc[0] + sc[1]) * (1.0f / 128.0f);
        ha[t] = fmaxf(d / sqrtf(var + 1e-5f) * alg[t] + alb[t], 0.f);
    }
    __syncthreads();
    for (int o = t; o < 512; o += 128) {
        float sm = mb2[o], sa = ab2[o];
        for (int p = 0; p < 128; ++p) {
            sm = fmaf(hm[p], mw2[o * 128 + p], sm);
            sa = fmaf(ha[p], aw2[o * 128 + p], sa);
        }
        mulo[b * 512 + o] = 1.0f / (1.0f + expf(-sm));
        addo[b * 512 + o] = sa;
    }
}

// ---------------- glob = x*mul + add (per b,c) ----------------
__global__ __launch_bounds__(256) void glob_ew(
    const float* __restrict__ x, const float* __restrict__ mulv,
    const float* __restrict__ addv, float* __restrict__ g)
{
    const size_t idx = (size_t)blockIdx.x * 256 + threadIdx.x;  // over B*C*N/4 float4
    const int bc = (int)(idx / (NPIX / 4));
    const float m = mulv[bc], a = addv[bc];
    const float4 xv = reinterpret_cast<const float4*>(x)[idx];
    reinterpret_cast<float4*>(g)[idx] =
        make_float4(fmaf(xv.x, m, a), fmaf(xv.y, m, a), fmaf(xv.z, m, a), fmaf(xv.w, m, a));
}

// ---------------- per-row softmax + exact top-k mean (binary search on bits) ----------------
__global__ __launch_bounds__(256) void softmax_topk(
    float* __restrict__ p, float* __restrict__ soft)
{
    __shared__ float row[NPIX];
    __shared__ float sc[4];
    __shared__ int   sci[4];
    const int m = blockIdx.x;
    float* pr = p + (size_t)m * NPIX;
    const int t = threadIdx.x;
    float mx = -3.4e38f;
    for (int i = t; i < NPIX; i += 256) { const float v = pr[i]; row[i] = v; mx = fmaxf(mx, v); }
    mx = blockMax256(mx, sc);
    __syncthreads();
    float s = 0.f;
    for (int i = t; i < NPIX; i += 256) { const float e = expf(row[i] - mx); row[i] = e; s += e; }
    s = blockSum256(s, sc);
    const float inv = 1.0f / s;
    __syncthreads();
    for (int i = t; i < NPIX; i += 256) { const float v = row[i] * inv; row[i] = v; pr[i] = v; }
    __syncthreads();
    // exact k-th largest via binary search on nonneg-float bit order
    unsigned lo = 0u, hi = 0x3F800000u;  // [0, 1.0]
    while (lo < hi) {
        const unsigned mid = lo + ((hi - lo + 1u) >> 1);
        const float tv = __uint_as_float(mid);
        int c = 0;
        for (int i = t; i < NPIX; i += 256) c += (row[i] >= tv) ? 1 : 0;
        c = blockSumI256(c, sci);
        if (c >= KNUM) lo = mid; else hi = mid - 1u;
    }
    const float tv = __uint_as_float(lo);
    float ssum = 0.f; int a = 0;
    for (int i = t; i < NPIX; i += 256) {
        const float v = row[i];
        if (v > tv) { ssum += v; a++; }
    }
    ssum = blockSum256(ssum, sc);
    a = blockSumI256(a, sci);
    if (t == 0) soft[m] = (ssum + (float)(KNUM - a) * tv) * (1.0f / (float)KNUM);
}

__global__ __launch_bounds__(256) void colsum_acc(
    const float* __restrict__ p, float* __restrict__ colsum)
{
    const int n = blockIdx.x * 256 + threadIdx.x;        // < 2304
    const int m0 = blockIdx.y * 72;
    float s = 0.f;
    for (int m = m0; m < m0 + 72; ++m) s += p[(size_t)m * NPIX + n];
    atomicAdd(&colsum[n], s);
}

__global__ __launch_bounds__(256) void zero_kernel(float* __restrict__ p, int n)
{
    const int i = blockIdx.x * 256 + threadIdx.x;
    if (i < n) p[i] = 0.f;
}

// ctx2[b,c] = (1/N) * sum_n v[b,c,n] * colsum[b,n] * soft[b,n]
__global__ __launch_bounds__(256) void ctx2_pool(
    const float* __restrict__ v, const float* __restrict__ colsum,
    const float* __restrict__ soft, float* __restrict__ ctx2)
{
    const int lane = threadIdx.x & 63, w = threadIdx.x >> 6;
    const int c = blockIdx.x * 4 + w;
    const int b = blockIdx.y;
    const float* vr = v + ((size_t)(b * NCH + c)) * NPIX;
    const float* cs = colsum + (size_t)b * NPIX;
    const float* sf = soft + (size_t)b * NPIX;
    float s = 0.f;
    for (int i = lane; i < NPIX; i += 64) s = fmaf(vr[i], cs[i] * sf[i], s);
    s = waveSum(s);
    if (lane == 0) ctx2[b * NCH + c] = s * (1.0f / (float)NPIX);
}

// z[b,o] = sum_c fin_w[o, 512+c] * ctx2[b,c]
__global__ __launch_bounds__(256) void compute_z(
    const float* __restrict__ finw, const float* __restrict__ ctx2, float* __restrict__ z)
{
    const int o = blockIdx.x * 256 + threadIdx.x;        // < 512
    const int b = blockIdx.y;
    const float* c2 = ctx2 + b * 512;
    const float* wr = finw + (size_t)o * 1024 + 512;
    float s = 0.f;
    for (int c = 0; c < 512; ++c) s = fmaf(wr[c], c2[c], s);
    z[b * 512 + o] = s;
}

// ---------------- host launcher ----------------
extern "C" void kernel_launch(void* const* d_in, const int* in_sizes, int n_in,
                              void* d_out, int out_size, void* d_ws, size_t ws_size,
                              hipStream_t stream)
{
    const float* x      = (const float*)d_in[0];
    const float* lb_w1  = (const float*)d_in[1];
    const float* lb_g1  = (const float*)d_in[2];
    const float* lb_b1  = (const float*)d_in[3];
    const float* lb_w2  = (const float*)d_in[4];
    const float* lb_g2  = (const float*)d_in[5];
    const float* lb_b2  = (const float*)d_in[6];
    const float* lb_w3  = (const float*)d_in[7];
    const float* lb_g3  = (const float*)d_in[8];
    const float* lb_b3  = (const float*)d_in[9];
    const float* cm_w   = (const float*)d_in[10];
    const float* cm_b   = (const float*)d_in[11];
    const float* ca_w1  = (const float*)d_in[12];
    const float* ca_b1  = (const float*)d_in[13];
    const float* ca_lg  = (const float*)d_in[14];
    const float* ca_lb  = (const float*)d_in[15];
    const float* ca_w2  = (const float*)d_in[16];
    const float* ca_b2  = (const float*)d_in[17];
    const float* cmu_w1 = (const float*)d_in[18];
    const float* cmu_b1 = (const float*)d_in[19];
    const float* cmu_lg = (const float*)d_in[20];
    const float* cmu_lb = (const float*)d_in[21];
    const float* cmu_w2 = (const float*)d_in[22];
    const float* cmu_b2 = (const float*)d_in[23];
    const float* fu_w   = (const float*)d_in[24];
    const float* fu_b   = (const float*)d_in[25];
    // indices 26..37: sem/boundary heads + ReverseAttention — dead code (region == 1 always)
    const float* q_w    = (const float*)d_in[38];
    const float* k_w    = (const float*)d_in[39];
    const float* v_w    = (const float*)d_in[40];
    const float* fin_w  = (const float*)d_in[41];

    float* ws = (float*)d_ws;
    const size_t BIG = (size_t)NB * NCH * NPIX;          // 9,437,184 floats
    float* bufA   = ws;                                  // t1 -> local -> q|k
    float* bufB   = ws + BIG;                            // t2 -> glob -> attn p (per-b)
    float* bufC   = ws + 2 * BIG;                        // gx
    float* smallr = ws + 3 * BIG;
    float* logits = smallr;                              // 18432
    float* mask   = smallr + 18432;                      // 18432
    float* soft   = smallr + 36864;                      // 18432
    float* colsum = smallr + 55296;                      // 18432
    float* ctxb   = smallr + 73728;                      // 4096
    float* mulb   = smallr + 77824;                      // 4096
    float* addb   = smallr + 81920;                      // 4096
    float* ctx2b  = smallr + 86016;                      // 4096
    float* zbuf   = smallr + 90112;                      // 4096
    float* qbuf = bufA;
    float* kbuf = bufA + (size_t)NB * 128 * NPIX;        // fits: 2*2,359,296 < BIG
    float* pbuf = bufB;                                  // 2304*2304 = 5,308,416 < BIG
    float* vbuf = (float*)d_out;                         // v fully consumed before final GEMM

    const size_t SB = (size_t)NCH * NPIX;
    const float alpha_bn  = 1.0f / sqrtf(1.0f + 1e-5f);  // eval-BN scale factor
    const float inv_sqrtd = 0.08838834764831845f;        // 1/sqrt(128)

    // 1. t1 = relu(bn(W1 @ x))            -> bufA
    gemm_k<false><<<dim3(36, 8, 8), 256, 0, stream>>>(lb_w1, 512, x, SB, nullptr, 0,
        bufA, SB, lb_g1, lb_b1, nullptr, 512, 512, 1, alpha_bn);
    // 2. t2 = relu(bn(dw3x3(t1)))         -> bufB
    dwconv_bn_relu<<<dim3(36864), 256, 0, stream>>>(bufA, lb_w2, lb_g2, lb_b2, bufB);
    // 3. local = bn(W3 @ t2)              -> bufA
    gemm_k<false><<<dim3(36, 8, 8), 256, 0, stream>>>(lb_w3, 512, bufB, SB, nullptr, 0,
        bufA, SB, lb_g3, lb_b3, nullptr, 512, 512, 0, alpha_bn);
    // 4. ContextBlock pooling + channel MLPs
    mask_logits<<<dim3(72), 256, 0, stream>>>(x, cm_w, cm_b, logits);
    softmax_mask<<<dim3(8), 256, 0, stream>>>(logits, mask);
    ctx_pool<<<dim3(128, 8), 256, 0, stream>>>(x, mask, ctxb);
    chan_mlps<<<dim3(8), 128, 0, stream>>>(ctxb,
        cmu_w1, cmu_b1, cmu_lg, cmu_lb, cmu_w2, cmu_b2,
        ca_w1, ca_b1, ca_lg, ca_lb, ca_w2, ca_b2,
        mulb, addb);
    // 5. glob = x*mul + add               -> bufB
    glob_ew<<<dim3(9216), 256, 0, stream>>>(x, mulb, addb, bufB);
    // 6. gx = fu_w @ [local; glob] + fu_b -> bufC
    gemm_k<false><<<dim3(36, 8, 8), 256, 0, stream>>>(fu_w, 1024, bufA, SB, bufB, SB,
        bufC, SB, nullptr, fu_b, nullptr, 512, 1024, 0, 1.0f);
    // 7. q, k, v projections
    gemm_k<false><<<dim3(36, 2, 8), 256, 0, stream>>>(q_w, 512, bufC, SB, nullptr, 0,
        qbuf, (size_t)128 * NPIX, nullptr, nullptr, nullptr, 128, 512, 0, 1.0f);
    gemm_k<false><<<dim3(36, 2, 8), 256, 0, stream>>>(k_w, 512, bufC, SB, nullptr, 0,
        kbuf, (size_t)128 * NPIX, nullptr, nullptr, nullptr, 128, 512, 0, 1.0f);
    gemm_k<false><<<dim3(36, 8, 8), 256, 0, stream>>>(v_w, 512, bufC, SB, nullptr, 0,
        vbuf, SB, nullptr, nullptr, nullptr, 512, 512, 0, 1.0f);
    // 8. attention: per-b attn GEMM -> softmax+topk -> column sums
    zero_kernel<<<dim3(72), 256, 0, stream>>>(colsum, NB * NPIX);
    for (int bb = 0; bb < NB; ++bb) {
        gemm_k<true><<<dim3(36, 36, 1), 256, 0, stream>>>(qbuf + (size_t)bb * 128 * NPIX, NPIX,
            kbuf + (size_t)bb * 128 * NPIX, 0, nullptr, 0,
            pbuf, 0, nullptr, nullptr, nullptr, NPIX, 128, 0, inv_sqrtd);
        softmax_topk<<<dim3(NPIX), 256, 0, stream>>>(pbuf, soft + (size_t)bb * NPIX);
        colsum_acc<<<dim3(9, 32), 256, 0, stream>>>(pbuf, colsum + (size_t)bb * NPIX);
    }
    // 9. ctx2, rank-1 bias z, final GEMM -> d_out
    ctx2_pool<<<dim3(128, 8), 256, 0, stream>>>(vbuf, colsum, soft, ctx2b);
    compute_z<<<dim3(2, 8), 256, 0, stream>>>(fin_w, ctx2b, zbuf);
    gemm_k<false><<<dim3(36, 8, 8), 256, 0, stream>>>(fin_w, 1024, bufC, SB, nullptr, 0,
        (float*)d_out, SB, nullptr, nullptr, zbuf, 512, 512, 0, 1.0f);
}

// Round 2
// 549.793 us; speedup vs baseline: 3.4386x; 3.4386x over previous
//
#include <hip/hip_runtime.h>
#include <math.h>

#define NPIX 2304
#define NCH  512
#define NB   8
#define KNUM 230

typedef unsigned short u16;
typedef __attribute__((ext_vector_type(8))) short short8v;
typedef __attribute__((ext_vector_type(4))) float float4v;

__device__ __forceinline__ float bf2f(u16 u) {
    union { unsigned v; float f; } x; x.v = ((unsigned)u) << 16; return x.f;
}
__device__ __forceinline__ u16 f2bf(float f) {
    union { float f; unsigned v; } x; x.f = f;
    unsigned r = x.v + 0x7FFFu + ((x.v >> 16) & 1u);   // RNE
    return (u16)(r >> 16);
}

// ---------------- reductions ----------------
__device__ __forceinline__ float waveSum(float v) {
    #pragma unroll
    for (int o = 32; o > 0; o >>= 1) v += __shfl_down(v, o);
    return v;
}
__device__ __forceinline__ float blockSum256(float v, float* sc4) {
    v = waveSum(v);
    __syncthreads();
    if ((threadIdx.x & 63) == 0) sc4[threadIdx.x >> 6] = v;
    __syncthreads();
    return sc4[0] + sc4[1] + sc4[2] + sc4[3];
}
__device__ __forceinline__ float waveMaxF(float v) {
    #pragma unroll
    for (int o = 32; o > 0; o >>= 1) v = fmaxf(v, __shfl_down(v, o));
    return v;
}
__device__ __forceinline__ float blockMax256(float v, float* sc4) {
    v = waveMaxF(v);
    __syncthreads();
    if ((threadIdx.x & 63) == 0) sc4[threadIdx.x >> 6] = v;
    __syncthreads();
    return fmaxf(fmaxf(sc4[0], sc4[1]), fmaxf(sc4[2], sc4[3]));
}

// ---------------- async global->LDS 16B ----------------
__device__ __forceinline__ void gl_lds16(const u16* g, u16* l) {
    __builtin_amdgcn_global_load_lds(
        reinterpret_cast<const unsigned __attribute__((address_space(1)))*>(
            reinterpret_cast<uintptr_t>(g)),
        reinterpret_cast<unsigned __attribute__((address_space(3)))*>(
            reinterpret_cast<uintptr_t>(l)),
        16, 0, 0);
}

// ---------------- bf16 MFMA GEMM ----------------
// D[R, Cl] = alpha*scaleR[R] * sum_k A[R,k]*B[Cl,k] + biasR[R] + biasC[b,Cl]
// A, B row-major, k contiguous. Output stored out[b][Cl][R] (R contiguous).
// flags: 1 = relu, 2 = fp32 output (else bf16).
// B1: second source for k >= 512 (channel concat).
__global__ __launch_bounds__(256, 2) void mfma_gemm(
    const u16* __restrict__ A, int ldA, long sA,
    const u16* __restrict__ B0, const u16* __restrict__ B1, int ldB, long sB,
    void* __restrict__ outp, int ldO, long sO,
    const float* __restrict__ scaleR, const float* __restrict__ biasR,
    const float* __restrict__ biasC, int ldbc,
    int K, float alpha, int flags)
{
    __shared__ u16 lA[128 * 64];
    __shared__ u16 lB[128 * 64];
    const int t  = threadIdx.x;
    const int w  = t >> 6, l = t & 63;
    const int wR = w >> 1, wC = w & 1;
    const int lg = l >> 4, lr = l & 15, l7 = l & 7;
    const int b   = blockIdx.z;
    const int Cl0 = blockIdx.x * 128;
    const int R0  = blockIdx.y * 128;
    const u16* Ab  = A + (size_t)b * sA;
    const u16* B0b = B0 + (size_t)b * sB;
    const u16* B1b = B1 ? B1 + (size_t)b * sB : nullptr;

    float4v acc[4][4];
    const float4v zero = {0.f, 0.f, 0.f, 0.f};
    #pragma unroll
    for (int i = 0; i < 4; ++i)
        #pragma unroll
        for (int j = 0; j < 4; ++j) acc[i][j] = zero;

    const int sr = t >> 3;     // staging row-in-issue (0..31)
    const int sp = t & 7;      // physical 16B chunk

    for (int k0 = 0; k0 < K; k0 += 64) {
        const u16* Bsrc = B0b; int kb = k0;
        if (B1b && k0 >= 512) { Bsrc = B1b; kb = k0 - 512; }
        #pragma unroll
        for (int i = 0; i < 4; ++i) {
            const int r  = i * 32 + sr;
            const int ca = sp ^ (r & 7);                  // pre-swizzled source chunk
            gl_lds16(Ab   + (size_t)(R0  + r) * ldA + (k0 + ca * 8), &lA[i * 2048 + t * 8]);
            gl_lds16(Bsrc + (size_t)(Cl0 + r) * ldB + (kb + ca * 8), &lB[i * 2048 + t * 8]);
        }
        __syncthreads();
        #pragma unroll
        for (int kk = 0; kk < 2; ++kk) {
            short8v af[4], bfv[4];
            const int p = (kk * 4 + lg) ^ l7;             // swizzled read chunk
            #pragma unroll
            for (int mt = 0; mt < 4; ++mt) {
                const int rA = wR * 64 + mt * 16 + lr;
                af[mt]  = *reinterpret_cast<const short8v*>(&lA[rA * 64 + p * 8]);
                const int rB = wC * 64 + mt * 16 + lr;
                bfv[mt] = *reinterpret_cast<const short8v*>(&lB[rB * 64 + p * 8]);
            }
            #pragma unroll
            for (int mt = 0; mt < 4; ++mt)
                #pragma unroll
                for (int nt = 0; nt < 4; ++nt)
                    acc[mt][nt] = __builtin_amdgcn_mfma_f32_16x16x32_bf16(
                        af[mt], bfv[nt], acc[mt][nt], 0, 0, 0);
        }
        __syncthreads();
    }

    const bool relu = (flags & 1), f32o = (flags & 2);
    #pragma unroll
    for (int nt = 0; nt < 4; ++nt) {
        const int Cl = Cl0 + wC * 64 + nt * 16 + lr;
        const float bc = biasC ? biasC[(size_t)b * ldbc + Cl] : 0.f;
        #pragma unroll
        for (int mt = 0; mt < 4; ++mt) {
            const int Rb = R0 + wR * 64 + mt * 16 + lg * 4;
            float4 scv = scaleR ? *reinterpret_cast<const float4*>(&scaleR[Rb])
                                : make_float4(1.f, 1.f, 1.f, 1.f);
            float4 bv  = biasR  ? *reinterpret_cast<const float4*>(&biasR[Rb])
                                : make_float4(0.f, 0.f, 0.f, 0.f);
            float vals[4];
            #pragma unroll
            for (int j = 0; j < 4; ++j) {
                const float sc = alpha * ((&scv.x)[j]);
                float v = acc[mt][nt][j] * sc + (&bv.x)[j] + bc;
                if (relu) v = fmaxf(v, 0.f);
                vals[j] = v;
            }
            if (f32o) {
                float* op = (float*)outp + (size_t)b * sO + (size_t)Cl * ldO + Rb;
                *reinterpret_cast<float4*>(op) = make_float4(vals[0], vals[1], vals[2], vals[3]);
            } else {
                ushort4 u;
                u.x = f2bf(vals[0]); u.y = f2bf(vals[1]);
                u.z = f2bf(vals[2]); u.w = f2bf(vals[3]);
                u16* op = (u16*)outp + (size_t)b * sO + (size_t)Cl * ldO + Rb;
                *reinterpret_cast<ushort4*>(op) = u;
            }
        }
    }
}

// ---------------- transpose+convert x: [b][c][n] f32 -> [b][n][c] bf16 ----------------
__global__ __launch_bounds__(256) void transpose_cvt(
    const float* __restrict__ x, u16* __restrict__ xb)
{
    __shared__ float tile[64][65];
    const int t = threadIdx.x;
    const int n0 = blockIdx.x * 64, c0 = blockIdx.y * 64, b = blockIdx.z;
    const int tr = t >> 4, tc4 = (t & 15) * 4;
    #pragma unroll
    for (int i = 0; i < 4; ++i) {
        const int cc = tr + i * 16;
        float4 v = *reinterpret_cast<const float4*>(
            x + ((size_t)(b * NCH + c0 + cc)) * NPIX + n0 + tc4);
        tile[cc][tc4 + 0] = v.x; tile[cc][tc4 + 1] = v.y;
        tile[cc][tc4 + 2] = v.z; tile[cc][tc4 + 3] = v.w;
    }
    __syncthreads();
    #pragma unroll
    for (int i = 0; i < 4; ++i) {
        const int nn = tr + i * 16;
        ushort4 u;
        u.x = f2bf(tile[tc4 + 0][nn]); u.y = f2bf(tile[tc4 + 1][nn]);
        u.z = f2bf(tile[tc4 + 2][nn]); u.w = f2bf(tile[tc4 + 3][nn]);
        *reinterpret_cast<ushort4*>(xb + ((size_t)b * NPIX + n0 + nn) * NCH + c0 + tc4) = u;
    }
}

// ---------------- f32 -> bf16 convert (n4 float4 groups) ----------------
__global__ __launch_bounds__(256) void cvt_bf16(
    const float* __restrict__ s, u16* __restrict__ d, int n4)
{
    const int i = blockIdx.x * 256 + threadIdx.x;
    if (i < n4) {
        float4 v = reinterpret_cast<const float4*>(s)[i];
        ushort4 u; u.x = f2bf(v.x); u.y = f2bf(v.y); u.z = f2bf(v.z); u.w = f2bf(v.w);
        reinterpret_cast<ushort4*>(d)[i] = u;
    }
}

// ---------------- fold BN scale into dw weights, tap-major ----------------
__global__ __launch_bounds__(256) void fold_dw(
    const float* __restrict__ wsrc, const float* __restrict__ g, float* __restrict__ wf)
{
    const int i = blockIdx.x * 256 + threadIdx.x;
    if (i < 9 * NCH) {
        const int c = i / 9, tap = i % 9;
        wf[tap * NCH + c] = wsrc[i] * g[c] * 0.99999500003749978f;
    }
}

// ---------------- depthwise 3x3 + BN + ReLU, [n][c] bf16 ----------------
__global__ __launch_bounds__(256) void dwconv_k(
    const u16* __restrict__ t1, const float* __restrict__ wf,
    const float* __restrict__ b2, u16* __restrict__ t2)
{
    const int idx = blockIdx.x * 256 + threadIdx.x;
    const int cq = idx & 127;
    const int n  = (idx >> 7) % NPIX;
    const int b  = (idx >> 7) / NPIX;
    const int c  = cq * 4;
    const int y = n / 48, x = n % 48;
    float s0 = 0.f, s1 = 0.f, s2 = 0.f, s3 = 0.f;
    #pragma unroll
    for (int dy = -1; dy <= 1; ++dy) {
        const int yy = y + dy;
        if (yy < 0 || yy >= 48) continue;
        #pragma unroll
        for (int dx = -1; dx <= 1; ++dx) {
            const int xx = x + dx;
            if (xx < 0 || xx >= 48) continue;
            ushort4 tv = *reinterpret_cast<const ushort4*>(
                &t1[((size_t)b * NPIX + yy * 48 + xx) * NCH + c]);
            float4 wv = *reinterpret_cast<const float4*>(
                &wf[((dy + 1) * 3 + dx + 1) * NCH + c]);
            s0 = fmaf(bf2f(tv.x), wv.x, s0); s1 = fmaf(bf2f(tv.y), wv.y, s1);
            s2 = fmaf(bf2f(tv.z), wv.z, s2); s3 = fmaf(bf2f(tv.w), wv.w, s3);
        }
    }
    float4 bb = *reinterpret_cast<const float4*>(&b2[c]);
    ushort4 o;
    o.x = f2bf(fmaxf(s0 + bb.x, 0.f)); o.y = f2bf(fmaxf(s1 + bb.y, 0.f));
    o.z = f2bf(fmaxf(s2 + bb.z, 0.f)); o.w = f2bf(fmaxf(s3 + bb.w, 0.f));
    *reinterpret_cast<ushort4*>(&t2[((size_t)b * NPIX + n) * NCH + c]) = o;
}

// ---------------- ContextBlock ----------------
__global__ __launch_bounds__(256) void mask_logits_k(
    const u16* __restrict__ xb, const float* __restrict__ cmw,
    const float* __restrict__ cmb, float* __restrict__ logits)
{
    const int w = threadIdx.x >> 6, l = threadIdx.x & 63;
    const int n = blockIdx.x * 4 + w, b = blockIdx.y;
    const ushort4* row = reinterpret_cast<const ushort4*>(xb + ((size_t)b * NPIX + n) * NCH);
    const int c0 = l * 8;
    ushort4 u0 = row[l * 2], u1 = row[l * 2 + 1];
    float4 w0 = *reinterpret_cast<const float4*>(&cmw[c0]);
    float4 w1 = *reinterpret_cast<const float4*>(&cmw[c0 + 4]);
    float s = bf2f(u0.x) * w0.x + bf2f(u0.y) * w0.y + bf2f(u0.z) * w0.z + bf2f(u0.w) * w0.w
            + bf2f(u1.x) * w1.x + bf2f(u1.y) * w1.y + bf2f(u1.z) * w1.z + bf2f(u1.w) * w1.w;
    s = waveSum(s);
    if (l == 0) logits[(size_t)b * NPIX + n] = s + cmb[0];
}

__global__ __launch_bounds__(256) void softmax_mask(
    const float* __restrict__ logits, float* __restrict__ mask)
{
    __shared__ float sc[4];
    const int b = blockIdx.x, t = threadIdx.x;
    const float* lr = logits + (size_t)b * NPIX;
    float mx = -3.4e38f;
    for (int i = t; i < NPIX; i += 256) mx = fmaxf(mx, lr[i]);
    mx = blockMax256(mx, sc);
    float s = 0.f;
    for (int i = t; i < NPIX; i += 256) s += __expf(lr[i] - mx);
    s = blockSum256(s, sc);
    const float inv = 1.0f / s;
    for (int i = t; i < NPIX; i += 256) mask[(size_t)b * NPIX + i] = __expf(lr[i] - mx) * inv;
}

__global__ __launch_bounds__(512) void ctx_pool_k(
    const u16* __restrict__ xb, const float* __restrict__ mask, float* __restrict__ ctx)
{
    const int c = threadIdx.x, b = blockIdx.y;
    const int nn0 = blockIdx.x * 128;
    float s = 0.f;
    for (int n = nn0; n < nn0 + 128; ++n)
        s = fmaf(bf2f(xb[((size_t)b * NPIX + n) * NCH + c]), mask[(size_t)b * NPIX + n], s);
    atomicAdd(&ctx[b * NCH + c], s);
}

__global__ __launch_bounds__(128) void chan_mlps(
    const float* __restrict__ ctxv,
    const float* __restrict__ mw1, const float* __restrict__ mb1,
    const float* __restrict__ mlg, const float* __restrict__ mlb,
    const float* __restrict__ mw2, const float* __restrict__ mb2,
    const float* __restrict__ aw1, const float* __restrict__ ab1,
    const float* __restrict__ alg, const float* __restrict__ alb,
    const float* __restrict__ aw2, const float* __restrict__ ab2,
    float* __restrict__ mulo, float* __restrict__ addo)
{
    __shared__ float cs[512];
    __shared__ float hm[128], ha[128];
    __shared__ float sc[2];
    const int b = blockIdx.x, t = threadIdx.x;
    for (int i = t; i < 512; i += 128) cs[i] = ctxv[b * 512 + i];
    __syncthreads();
    float hmv = mb1[t], hav = ab1[t];
    for (int c = 0; c < 512; ++c) {
        const float cv = cs[c];
        hmv = fmaf(cv, mw1[t * 512 + c], hmv);
        hav = fmaf(cv, aw1[t * 512 + c], hav);
    }
    {
        float s1 = waveSum(hmv);
        __syncthreads();
        if ((t & 63) == 0) sc[t >> 6] = s1;
        __syncthreads();
        const float mu = (sc[0] + sc[1]) * (1.0f / 128.0f);
        const float d = hmv - mu;
        float s2 = waveSum(d * d);
        __syncthreads();
        if ((t & 63) == 0) sc[t >> 6] = s2;
        __syncthreads();
        const float var = (sc[0] + sc[1]) * (1.0f / 128.0f);
        hm[t] = fmaxf(d / sqrtf(var + 1e-5f) * mlg[t] + mlb[t], 0.f);
    }
    {
        float s1 = waveSum(hav);
        __syncthreads();
        if ((t & 63) == 0) sc[t >> 6] = s1;
        __syncthreads();
        const float mu = (sc[0] + sc[1]) * (1.0f / 128.0f);
        const float d = hav - mu;
        float s2 = waveSum(d * d);
        __syncthreads();
        if ((t & 63) == 0) sc[t >> 6] = s2;
        __syncthreads();
        const float var = (sc[0] + sc[1]) * (1.0f / 128.0f);
        ha[t] = fmaxf(d / sqrtf(var + 1e-5f) * alg[t] + alb[t], 0.f);
    }
    __syncthreads();
    for (int o = t; o < 512; o += 128) {
        float sm = mb2[o], sa = ab2[o];
        for (int p = 0; p < 128; ++p) {
            sm = fmaf(hm[p], mw2[o * 128 + p], sm);
            sa = fmaf(ha[p], aw2[o * 128 + p], sa);
        }
        mulo[b * 512 + o] = 1.0f / (1.0f + __expf(-sm));
        addo[b * 512 + o] = sa;
    }
}

__global__ __launch_bounds__(256) void glob_ew_k(
    const u16* __restrict__ xb, const float* __restrict__ mulv,
    const float* __restrict__ addv, u16* __restrict__ g)
{
    const int idx = blockIdx.x * 256 + threadIdx.x;
    const int cq = idx & 63;
    const int n = (idx >> 6) % NPIX;
    const int b = (idx >> 6) / NPIX;
    const int c = cq * 8;
    const size_t base = ((size_t)b * NPIX + n) * NCH + c;
    ushort4 u0 = *reinterpret_cast<const ushort4*>(&xb[base]);
    ushort4 u1 = *reinterpret_cast<const ushort4*>(&xb[base + 4]);
    const float* mp = &mulv[b * NCH + c];
    const float* ap = &addv[b * NCH + c];
    float4 m0 = *reinterpret_cast<const float4*>(mp);
    float4 m1 = *reinterpret_cast<const float4*>(mp + 4);
    float4 a0 = *reinterpret_cast<const float4*>(ap);
    float4 a1 = *reinterpret_cast<const float4*>(ap + 4);
    ushort4 o0, o1;
    o0.x = f2bf(fmaf(bf2f(u0.x), m0.x, a0.x));
    o0.y = f2bf(fmaf(bf2f(u0.y), m0.y, a0.y));
    o0.z = f2bf(fmaf(bf2f(u0.z), m0.z, a0.z));
    o0.w = f2bf(fmaf(bf2f(u0.w), m0.w, a0.w));
    o1.x = f2bf(fmaf(bf2f(u1.x), m1.x, a1.x));
    o1.y = f2bf(fmaf(bf2f(u1.y), m1.y, a1.y));
    o1.z = f2bf(fmaf(bf2f(u1.z), m1.z, a1.z));
    o1.w = f2bf(fmaf(bf2f(u1.w), m1.w, a1.w));
    *reinterpret_cast<ushort4*>(&g[base]) = o0;
    *reinterpret_cast<ushort4*>(&g[base + 4]) = o1;
}

// ---------------- wave-per-row softmax + exact top-k ----------------
__global__ __launch_bounds__(256) void softmax_topk_wave(
    const u16* __restrict__ p, float* __restrict__ mxo,
    float* __restrict__ invSo, float* __restrict__ softo, int bOff)
{
    const int w = threadIdx.x >> 6, l = threadIdx.x & 63;
    const int r = blockIdx.x * 4 + w;
    const int bc = blockIdx.y;
    const u16* pr = p + ((size_t)bc * NPIX + r) * NPIX;
    float e[36];
    float mx = -3.4e38f;
    #pragma unroll
    for (int i = 0; i < 36; ++i) { e[i] = bf2f(pr[i * 64 + l]); mx = fmaxf(mx, e[i]); }
    #pragma unroll
    for (int o = 32; o > 0; o >>= 1) mx = fmaxf(mx, __shfl_xor(mx, o));
    float S = 0.f;
    #pragma unroll
    for (int i = 0; i < 36; ++i) { e[i] = __expf(e[i] - mx); S += e[i]; }
    #pragma unroll
    for (int o = 32; o > 0; o >>= 1) S += __shfl_xor(S, o);
    const float invS = 1.0f / S;
    unsigned lo = 0u, hi = 0x3F800000u;
    while (lo < hi) {
        const unsigned mid = lo + ((hi - lo + 1u) >> 1);
        const float tv = __uint_as_float(mid);
        int c = 0;
        #pragma unroll
        for (int i = 0; i < 36; ++i) c += (e[i] >= tv) ? 1 : 0;
        #pragma unroll
        for (int o = 32; o > 0; o >>= 1) c += __shfl_xor(c, o);
        if (c >= KNUM) lo = mid; else hi = mid - 1u;
    }
    const float tv = __uint_as_float(lo);
    float ss = 0.f; int a = 0;
    #pragma unroll
    for (int i = 0; i < 36; ++i) { if (e[i] > tv) { ss += e[i]; a++; } }
    #pragma unroll
    for (int o = 32; o > 0; o >>= 1) { ss += __shfl_xor(ss, o); a += __shfl_xor(a, o); }
    if (l == 0) {
        const size_t gi = (size_t)(bOff + bc) * NPIX + r;
        mxo[gi] = mx; invSo[gi] = invS;
        softo[gi] = (ss + (float)(KNUM - a) * tv) * invS * (1.0f / (float)KNUM);
    }
}

__global__ __launch_bounds__(256) void colsum_k(
    const u16* __restrict__ p, const float* __restrict__ mxo,
    const float* __restrict__ invSo, float* __restrict__ colsum, int bOff)
{
    const int j = blockIdx.x * 256 + threadIdx.x;
    const int ic0 = blockIdx.y * 576;
    const int bc = blockIdx.z;
    const float* mxr = mxo + (size_t)(bOff + bc) * NPIX;
    const float* isr = invSo + (size_t)(bOff + bc) * NPIX;
    const u16* pb = p + (size_t)bc * NPIX * NPIX;
    float s = 0.f;
    for (int i = ic0; i < ic0 + 576; ++i)
        s += __expf(bf2f(pb[(size_t)i * NPIX + j]) - mxr[i]) * isr[i];
    atomicAdd(&colsum[(size_t)(bOff + bc) * NPIX + j], s);
}

__global__ __launch_bounds__(512) void ctx2_pool_k(
    const u16* __restrict__ qkv, const float* __restrict__ colsum,
    const float* __restrict__ soft, float* __restrict__ ctx2)
{
    const int c = threadIdx.x, b = blockIdx.y;
    const int nn0 = blockIdx.x * 128;
    float s = 0.f;
    for (int n = nn0; n < nn0 + 128; ++n) {
        const float wgt = colsum[(size_t)b * NPIX + n] * soft[(size_t)b * NPIX + n];
        s = fmaf(bf2f(qkv[((size_t)b * NPIX + n) * 768 + 256 + c]), wgt, s);
    }
    atomicAdd(&ctx2[b * NCH + c], s * (1.0f / (float)NPIX));
}

__global__ __launch_bounds__(256) void compute_z(
    const float* __restrict__ finw, const float* __restrict__ ctx2, float* __restrict__ z)
{
    const int o = blockIdx.x * 256 + threadIdx.x;
    const int b = blockIdx.y;
    const float* c2 = ctx2 + b * NCH;
    const float* wr = finw + (size_t)o * 1024 + 512;
    float s = 0.f;
    for (int c = 0; c < NCH; ++c) s = fmaf(wr[c], c2[c], s);
    z[b * NCH + o] = s;
}

// ---------------- host launcher ----------------
extern "C" void kernel_launch(void* const* d_in, const int* in_sizes, int n_in,
                              void* d_out, int out_size, void* d_ws, size_t ws_size,
                              hipStream_t stream)
{
    (void)in_sizes; (void)n_in; (void)out_size; (void)ws_size;
    const float* x      = (const float*)d_in[0];
    const float* lb_w1  = (const float*)d_in[1];
    const float* lb_g1  = (const float*)d_in[2];
    const float* lb_b1  = (const float*)d_in[3];
    const float* lb_w2  = (const float*)d_in[4];
    const float* lb_g2  = (const float*)d_in[5];
    const float* lb_b2  = (const float*)d_in[6];
    const float* lb_w3  = (const float*)d_in[7];
    const float* lb_g3  = (const float*)d_in[8];
    const float* lb_b3  = (const float*)d_in[9];
    const float* cm_w   = (const float*)d_in[10];
    const float* cm_b   = (const float*)d_in[11];
    const float* ca_w1  = (const float*)d_in[12];
    const float* ca_b1  = (const float*)d_in[13];
    const float* ca_lg  = (const float*)d_in[14];
    const float* ca_lb  = (const float*)d_in[15];
    const float* ca_w2  = (const float*)d_in[16];
    const float* ca_b2  = (const float*)d_in[17];
    const float* cmu_w1 = (const float*)d_in[18];
    const float* cmu_b1 = (const float*)d_in[19];
    const float* cmu_lg = (const float*)d_in[20];
    const float* cmu_lb = (const float*)d_in[21];
    const float* cmu_w2 = (const float*)d_in[22];
    const float* cmu_b2 = (const float*)d_in[23];
    const float* fu_w   = (const float*)d_in[24];
    const float* fu_b   = (const float*)d_in[25];
    // 26..37 dead (region == 1 identically)
    const float* q_w    = (const float*)d_in[38];
    const float* k_w    = (const float*)d_in[39];
    const float* v_w    = (const float*)d_in[40];
    const float* fin_w  = (const float*)d_in[41];

    char* W = (char*)d_ws;
    const size_t SZ_ACT = (size_t)NB * NPIX * NCH * 2;     // 18,874,368 B
    u16* xb   = (u16*)(W);
    u16* bufA = (u16*)(W + SZ_ACT);                        // t1 -> local
    u16* bufB = (u16*)(W + 2 * SZ_ACT);                    // t2 -> glob
    u16* gx   = (u16*)(W + 3 * SZ_ACT);
    u16* qkv  = (u16*)(W + 4 * SZ_ACT);                    // [b][n][768]
    char* SM = W + 4 * SZ_ACT + (size_t)NB * NPIX * 768 * 2;
    float* logits = (float*)SM; SM += (size_t)NB * NPIX * 4;
    float* maskb  = (float*)SM; SM += (size_t)NB * NPIX * 4;
    float* mxb    = (float*)SM; SM += (size_t)NB * NPIX * 4;
    float* invSb  = (float*)SM; SM += (size_t)NB * NPIX * 4;
    float* softb  = (float*)SM; SM += (size_t)NB * NPIX * 4;
    float* colsum = (float*)SM; SM += (size_t)NB * NPIX * 4;  // zero region start
    float* ctxb   = (float*)SM; SM += (size_t)NB * NCH * 4;
    float* ctx2b  = (float*)SM; SM += (size_t)NB * NCH * 4;   // zero region end
    float* mulb   = (float*)SM; SM += (size_t)NB * NCH * 4;
    float* addb   = (float*)SM; SM += (size_t)NB * NCH * 4;
    float* zbuf   = (float*)SM; SM += (size_t)NB * NCH * 4;
    float* wfold  = (float*)SM; SM += (size_t)9 * NCH * 4;
    u16* w1b   = (u16*)SM; SM += (size_t)512 * 512 * 2;
    u16* w3b   = (u16*)SM; SM += (size_t)512 * 512 * 2;
    u16* fuwb  = (u16*)SM; SM += (size_t)512 * 1024 * 2;
    u16* finwb = (u16*)SM; SM += (size_t)512 * 1024 * 2;
    u16* qkvwb = (u16*)SM; SM += (size_t)768 * 512 * 2;
    u16* pbuf = xb;   // aliases pools 0-2 after they are dead (42.5MB < 56.6MB)

    const float invs  = 0.99999500003749978f;   // 1/sqrt(1+1e-5)
    const float rs128 = 0.08838834764831845f;   // 1/sqrt(128)
    const long SACT = (long)NPIX * NCH;

    // weight conversions
    cvt_bf16<<<256, 256, 0, stream>>>(lb_w1, w1b, 65536);
    cvt_bf16<<<256, 256, 0, stream>>>(lb_w3, w3b, 65536);
    cvt_bf16<<<512, 256, 0, stream>>>(fu_w, fuwb, 131072);
    cvt_bf16<<<512, 256, 0, stream>>>(fin_w, finwb, 131072);
    cvt_bf16<<<64, 256, 0, stream>>>(q_w, qkvwb, 16384);
    cvt_bf16<<<64, 256, 0, stream>>>(k_w, qkvwb + 128 * 512, 16384);
    cvt_bf16<<<256, 256, 0, stream>>>(v_w, qkvwb + 256 * 512, 65536);
    fold_dw<<<18, 256, 0, stream>>>(lb_w2, lb_g2, wfold);
    transpose_cvt<<<dim3(36, 8, 8), 256, 0, stream>>>(x, xb);
    hipMemsetAsync(colsum, 0, (size_t)NB * NPIX * 4 + 2 * (size_t)NB * NCH * 4, stream);

    // local branch
    mfma_gemm<<<dim3(18, 4, 8), 256, 0, stream>>>(w1b, 512, 0, xb, nullptr, 512, SACT,
        bufA, 512, SACT, lb_g1, lb_b1, nullptr, 0, 512, invs, 1);
    dwconv_k<<<9216, 256, 0, stream>>>(bufA, wfold, lb_b2, bufB);
    mfma_gemm<<<dim3(18, 4, 8), 256, 0, stream>>>(w3b, 512, 0, bufB, nullptr, 512, SACT,
        bufA, 512, SACT, lb_g3, lb_b3, nullptr, 0, 512, invs, 0);
    // ContextBlock
    mask_logits_k<<<dim3(576, 8), 256, 0, stream>>>(xb, cm_w, cm_b, logits);
    softmax_mask<<<8, 256, 0, stream>>>(logits, maskb);
    ctx_pool_k<<<dim3(18, 8), 512, 0, stream>>>(xb, maskb, ctxb);
    chan_mlps<<<8, 128, 0, stream>>>(ctxb,
        cmu_w1, cmu_b1, cmu_lg, cmu_lb, cmu_w2, cmu_b2,
        ca_w1, ca_b1, ca_lg, ca_lb, ca_w2, ca_b2, mulb, addb);
    glob_ew_k<<<4608, 256, 0, stream>>>(xb, mulb, addb, bufB);
    // fusion
    mfma_gemm<<<dim3(18, 4, 8), 256, 0, stream>>>(fuwb, 1024, 0, bufA, bufB, 512, SACT,
        gx, 512, SACT, nullptr, fu_b, nullptr, 0, 1024, 1.0f, 0);
    // q|k|v stacked projection
    mfma_gemm<<<dim3(18, 6, 8), 256, 0, stream>>>(qkvwb, 512, 0, gx, nullptr, 512, SACT,
        qkv, 768, (long)NPIX * 768, nullptr, nullptr, nullptr, 0, 512, 1.0f, 0);
    // attention in 2 chunks of 4 batches
    for (int cc = 0; cc < 2; ++cc) {
        const u16* kp = qkv + (size_t)cc * 4 * NPIX * 768 + 128;
        const u16* qp = qkv + (size_t)cc * 4 * NPIX * 768;
        mfma_gemm<<<dim3(18, 18, 4), 256, 0, stream>>>(kp, 768, (long)NPIX * 768,
            qp, nullptr, 768, (long)NPIX * 768,
            pbuf, NPIX, (long)NPIX * NPIX, nullptr, nullptr, nullptr, 0, 128, rs128, 0);
        softmax_topk_wave<<<dim3(576, 4), 256, 0, stream>>>(pbuf, mxb, invSb, softb, cc * 4);
        colsum_k<<<dim3(9, 4, 4), 256, 0, stream>>>(pbuf, mxb, invSb, colsum, cc * 4);
    }
    // epilogue path
    ctx2_pool_k<<<dim3(18, 8), 512, 0, stream>>>(qkv, colsum, softb, ctx2b);
    compute_z<<<dim3(2, 8), 256, 0, stream>>>(fin_w, ctx2b, zbuf);
    mfma_gemm<<<dim3(4, 18, 8), 256, 0, stream>>>(gx, 512, SACT, finwb, nullptr, 1024, 0,
        d_out, NPIX, (long)NCH * NPIX, nullptr, nullptr, zbuf, 512, 512, 1.0f, 2);
}

// Round 3
// 456.612 us; speedup vs baseline: 4.1403x; 1.2041x over previous
//
#include <hip/hip_runtime.h>
#include <math.h>

#define NPIX 2304
#define NCH  512
#define NB   8
#define KNUM 230

typedef unsigned short u16;
typedef __attribute__((ext_vector_type(8))) short short8v;
typedef __attribute__((ext_vector_type(4))) float float4v;

__device__ __forceinline__ float bf2f(u16 u) {
    union { unsigned v; float f; } x; x.v = ((unsigned)u) << 16; return x.f;
}
__device__ __forceinline__ u16 f2bf(float f) {
    union { float f; unsigned v; } x; x.f = f;
    unsigned r = x.v + 0x7FFFu + ((x.v >> 16) & 1u);   // RNE
    return (u16)(r >> 16);
}

// ---------------- reductions ----------------
__device__ __forceinline__ float waveSum(float v) {
    #pragma unroll
    for (int o = 32; o > 0; o >>= 1) v += __shfl_down(v, o);
    return v;
}
__device__ __forceinline__ float blockSum256(float v, float* sc4) {
    v = waveSum(v);
    __syncthreads();
    if ((threadIdx.x & 63) == 0) sc4[threadIdx.x >> 6] = v;
    __syncthreads();
    return sc4[0] + sc4[1] + sc4[2] + sc4[3];
}
__device__ __forceinline__ float waveMaxF(float v) {
    #pragma unroll
    for (int o = 32; o > 0; o >>= 1) v = fmaxf(v, __shfl_down(v, o));
    return v;
}
__device__ __forceinline__ float blockMax256(float v, float* sc4) {
    v = waveMaxF(v);
    __syncthreads();
    if ((threadIdx.x & 63) == 0) sc4[threadIdx.x >> 6] = v;
    __syncthreads();
    return fmaxf(fmaxf(sc4[0], sc4[1]), fmaxf(sc4[2], sc4[3]));
}

// ---------------- async global->LDS 16B ----------------
__device__ __forceinline__ void gl_lds16(const u16* g, u16* l) {
    __builtin_amdgcn_global_load_lds(
        reinterpret_cast<const unsigned __attribute__((address_space(1)))*>(
            reinterpret_cast<uintptr_t>(g)),
        reinterpret_cast<unsigned __attribute__((address_space(3)))*>(
            reinterpret_cast<uintptr_t>(l)),
        16, 0, 0);
}

// ---------------- bf16 MFMA GEMM ----------------
// D[R, Cl] = alpha*scaleR[R] * sum_k A[R,k]*B[Cl,k] + biasR[R] + biasC[b,Cl]
// A, B row-major, k contiguous. Output stored out[b][Cl][R] (R contiguous).
// flags: 1 = relu, 2 = fp32 output (else bf16).
// B1: second source for k >= 512 (channel concat).
__global__ __launch_bounds__(256, 2) void mfma_gemm(
    const u16* __restrict__ A, int ldA, long sA,
    const u16* __restrict__ B0, const u16* __restrict__ B1, int ldB, long sB,
    void* __restrict__ outp, int ldO, long sO,
    const float* __restrict__ scaleR, const float* __restrict__ biasR,
    const float* __restrict__ biasC, int ldbc,
    int K, float alpha, int flags)
{
    __shared__ u16 lA[128 * 64];
    __shared__ u16 lB[128 * 64];
    const int t  = threadIdx.x;
    const int w  = t >> 6, l = t & 63;
    const int wR = w >> 1, wC = w & 1;
    const int lg = l >> 4, lr = l & 15, l7 = l & 7;
    const int b   = blockIdx.z;
    const int Cl0 = blockIdx.x * 128;
    const int R0  = blockIdx.y * 128;
    const u16* Ab  = A + (size_t)b * sA;
    const u16* B0b = B0 + (size_t)b * sB;
    const u16* B1b = B1 ? B1 + (size_t)b * sB : nullptr;

    float4v acc[4][4];
    const float4v zero = {0.f, 0.f, 0.f, 0.f};
    #pragma unroll
    for (int i = 0; i < 4; ++i)
        #pragma unroll
        for (int j = 0; j < 4; ++j) acc[i][j] = zero;

    const int sr = t >> 3;     // staging row-in-issue (0..31)
    const int sp = t & 7;      // physical 16B chunk

    for (int k0 = 0; k0 < K; k0 += 64) {
        const u16* Bsrc = B0b; int kb = k0;
        if (B1b && k0 >= 512) { Bsrc = B1b; kb = k0 - 512; }
        #pragma unroll
        for (int i = 0; i < 4; ++i) {
            const int r  = i * 32 + sr;
            const int ca = sp ^ (r & 7);                  // pre-swizzled source chunk
            gl_lds16(Ab   + (size_t)(R0  + r) * ldA + (k0 + ca * 8), &lA[i * 2048 + t * 8]);
            gl_lds16(Bsrc + (size_t)(Cl0 + r) * ldB + (kb + ca * 8), &lB[i * 2048 + t * 8]);
        }
        __syncthreads();
        #pragma unroll
        for (int kk = 0; kk < 2; ++kk) {
            short8v af[4], bfv[4];
            const int p = (kk * 4 + lg) ^ l7;             // swizzled read chunk
            #pragma unroll
            for (int mt = 0; mt < 4; ++mt) {
                const int rA = wR * 64 + mt * 16 + lr;
                af[mt]  = *reinterpret_cast<const short8v*>(&lA[rA * 64 + p * 8]);
                const int rB = wC * 64 + mt * 16 + lr;
                bfv[mt] = *reinterpret_cast<const short8v*>(&lB[rB * 64 + p * 8]);
            }
            #pragma unroll
            for (int mt = 0; mt < 4; ++mt)
                #pragma unroll
                for (int nt = 0; nt < 4; ++nt)
                    acc[mt][nt] = __builtin_amdgcn_mfma_f32_16x16x32_bf16(
                        af[mt], bfv[nt], acc[mt][nt], 0, 0, 0);
        }
        __syncthreads();
    }

    const bool relu = (flags & 1), f32o = (flags & 2);
    #pragma unroll
    for (int nt = 0; nt < 4; ++nt) {
        const int Cl = Cl0 + wC * 64 + nt * 16 + lr;
        const float bc = biasC ? biasC[(size_t)b * ldbc + Cl] : 0.f;
        #pragma unroll
        for (int mt = 0; mt < 4; ++mt) {
            const int Rb = R0 + wR * 64 + mt * 16 + lg * 4;
            float4 scv = scaleR ? *reinterpret_cast<const float4*>(&scaleR[Rb])
                                : make_float4(1.f, 1.f, 1.f, 1.f);
            float4 bv  = biasR  ? *reinterpret_cast<const float4*>(&biasR[Rb])
                                : make_float4(0.f, 0.f, 0.f, 0.f);
            float vals[4];
            #pragma unroll
            for (int j = 0; j < 4; ++j) {
                const float sc = alpha * ((&scv.x)[j]);
                float v = acc[mt][nt][j] * sc + (&bv.x)[j] + bc;
                if (relu) v = fmaxf(v, 0.f);
                vals[j] = v;
            }
            if (f32o) {
                float* op = (float*)outp + (size_t)b * sO + (size_t)Cl * ldO + Rb;
                *reinterpret_cast<float4*>(op) = make_float4(vals[0], vals[1], vals[2], vals[3]);
            } else {
                ushort4 u;
                u.x = f2bf(vals[0]); u.y = f2bf(vals[1]);
                u.z = f2bf(vals[2]); u.w = f2bf(vals[3]);
                u16* op = (u16*)outp + (size_t)b * sO + (size_t)Cl * ldO + Rb;
                *reinterpret_cast<ushort4*>(op) = u;
            }
        }
    }
}

// ---------------- transpose+convert x: [b][c][n] f32 -> [b][n][c] bf16 ----------------
__global__ __launch_bounds__(256) void transpose_cvt(
    const float* __restrict__ x, u16* __restrict__ xb)
{
    __shared__ float tile[64][65];
    const int t = threadIdx.x;
    const int n0 = blockIdx.x * 64, c0 = blockIdx.y * 64, b = blockIdx.z;
    const int tr = t >> 4, tc4 = (t & 15) * 4;
    #pragma unroll
    for (int i = 0; i < 4; ++i) {
        const int cc = tr + i * 16;
        float4 v = *reinterpret_cast<const float4*>(
            x + ((size_t)(b * NCH + c0 + cc)) * NPIX + n0 + tc4);
        tile[cc][tc4 + 0] = v.x; tile[cc][tc4 + 1] = v.y;
        tile[cc][tc4 + 2] = v.z; tile[cc][tc4 + 3] = v.w;
    }
    __syncthreads();
    #pragma unroll
    for (int i = 0; i < 4; ++i) {
        const int nn = tr + i * 16;
        ushort4 u;
        u.x = f2bf(tile[tc4 + 0][nn]); u.y = f2bf(tile[tc4 + 1][nn]);
        u.z = f2bf(tile[tc4 + 2][nn]); u.w = f2bf(tile[tc4 + 3][nn]);
        *reinterpret_cast<ushort4*>(xb + ((size_t)b * NPIX + n0 + nn) * NCH + c0 + tc4) = u;
    }
}

// ---------------- f32 -> bf16 convert (n4 float4 groups) ----------------
__global__ __launch_bounds__(256) void cvt_bf16(
    const float* __restrict__ s, u16* __restrict__ d, int n4)
{
    const int i = blockIdx.x * 256 + threadIdx.x;
    if (i < n4) {
        float4 v = reinterpret_cast<const float4*>(s)[i];
        ushort4 u; u.x = f2bf(v.x); u.y = f2bf(v.y); u.z = f2bf(v.z); u.w = f2bf(v.w);
        reinterpret_cast<ushort4*>(d)[i] = u;
    }
}

// ---------------- fold BN scale into dw weights, tap-major ----------------
__global__ __launch_bounds__(256) void fold_dw(
    const float* __restrict__ wsrc, const float* __restrict__ g, float* __restrict__ wf)
{
    const int i = blockIdx.x * 256 + threadIdx.x;
    if (i < 9 * NCH) {
        const int c = i / 9, tap = i % 9;
        wf[tap * NCH + c] = wsrc[i] * g[c] * 0.99999500003749978f;
    }
}

// ---------------- depthwise 3x3 + BN + ReLU, [n][c] bf16 ----------------
__global__ __launch_bounds__(256) void dwconv_k(
    const u16* __restrict__ t1, const float* __restrict__ wf,
    const float* __restrict__ b2, u16* __restrict__ t2)
{
    const int idx = blockIdx.x * 256 + threadIdx.x;
    const int cq = idx & 127;
    const int n  = (idx >> 7) % NPIX;
    const int b  = (idx >> 7) / NPIX;
    const int c  = cq * 4;
    const int y = n / 48, x = n % 48;
    float s0 = 0.f, s1 = 0.f, s2 = 0.f, s3 = 0.f;
    #pragma unroll
    for (int dy = -1; dy <= 1; ++dy) {
        const int yy = y + dy;
        if (yy < 0 || yy >= 48) continue;
        #pragma unroll
        for (int dx = -1; dx <= 1; ++dx) {
            const int xx = x + dx;
            if (xx < 0 || xx >= 48) continue;
            ushort4 tv = *reinterpret_cast<const ushort4*>(
                &t1[((size_t)b * NPIX + yy * 48 + xx) * NCH + c]);
            float4 wv = *reinterpret_cast<const float4*>(
                &wf[((dy + 1) * 3 + dx + 1) * NCH + c]);
            s0 = fmaf(bf2f(tv.x), wv.x, s0); s1 = fmaf(bf2f(tv.y), wv.y, s1);
            s2 = fmaf(bf2f(tv.z), wv.z, s2); s3 = fmaf(bf2f(tv.w), wv.w, s3);
        }
    }
    float4 bb = *reinterpret_cast<const float4*>(&b2[c]);
    ushort4 o;
    o.x = f2bf(fmaxf(s0 + bb.x, 0.f)); o.y = f2bf(fmaxf(s1 + bb.y, 0.f));
    o.z = f2bf(fmaxf(s2 + bb.z, 0.f)); o.w = f2bf(fmaxf(s3 + bb.w, 0.f));
    *reinterpret_cast<ushort4*>(&t2[((size_t)b * NPIX + n) * NCH + c]) = o;
}

// ---------------- ContextBlock ----------------
__global__ __launch_bounds__(256) void mask_logits_k(
    const u16* __restrict__ xb, const float* __restrict__ cmw,
    const float* __restrict__ cmb, float* __restrict__ logits)
{
    const int w = threadIdx.x >> 6, l = threadIdx.x & 63;
    const int n = blockIdx.x * 4 + w, b = blockIdx.y;
    const ushort4* row = reinterpret_cast<const ushort4*>(xb + ((size_t)b * NPIX + n) * NCH);
    const int c0 = l * 8;
    ushort4 u0 = row[l * 2], u1 = row[l * 2 + 1];
    float4 w0 = *reinterpret_cast<const float4*>(&cmw[c0]);
    float4 w1 = *reinterpret_cast<const float4*>(&cmw[c0 + 4]);
    float s = bf2f(u0.x) * w0.x + bf2f(u0.y) * w0.y + bf2f(u0.z) * w0.z + bf2f(u0.w) * w0.w
            + bf2f(u1.x) * w1.x + bf2f(u1.y) * w1.y + bf2f(u1.z) * w1.z + bf2f(u1.w) * w1.w;
    s = waveSum(s);
    if (l == 0) logits[(size_t)b * NPIX + n] = s + cmb[0];
}

__global__ __launch_bounds__(256) void softmax_mask(
    const float* __restrict__ logits, float* __restrict__ mask)
{
    __shared__ float sc[4];
    const int b = blockIdx.x, t = threadIdx.x;
    const float* lr = logits + (size_t)b * NPIX;
    float mx = -3.4e38f;
    for (int i = t; i < NPIX; i += 256) mx = fmaxf(mx, lr[i]);
    mx = blockMax256(mx, sc);
    float s = 0.f;
    for (int i = t; i < NPIX; i += 256) s += __expf(lr[i] - mx);
    s = blockSum256(s, sc);
    const float inv = 1.0f / s;
    for (int i = t; i < NPIX; i += 256) mask[(size_t)b * NPIX + i] = __expf(lr[i] - mx) * inv;
}

__global__ __launch_bounds__(512) void ctx_pool_k(
    const u16* __restrict__ xb, const float* __restrict__ mask, float* __restrict__ ctx)
{
    const int c = threadIdx.x, b = blockIdx.y;
    const int nn0 = blockIdx.x * 128;
    float s = 0.f;
    for (int n = nn0; n < nn0 + 128; ++n)
        s = fmaf(bf2f(xb[((size_t)b * NPIX + n) * NCH + c]), mask[(size_t)b * NPIX + n], s);
    atomicAdd(&ctx[b * NCH + c], s);
}

__global__ __launch_bounds__(128) void chan_mlps(
    const float* __restrict__ ctxv,
    const float* __restrict__ mw1, const float* __restrict__ mb1,
    const float* __restrict__ mlg, const float* __restrict__ mlb,
    const float* __restrict__ mw2, const float* __restrict__ mb2,
    const float* __restrict__ aw1, const float* __restrict__ ab1,
    const float* __restrict__ alg, const float* __restrict__ alb,
    const float* __restrict__ aw2, const float* __restrict__ ab2,
    float* __restrict__ mulo, float* __restrict__ addo)
{
    __shared__ float cs[512];
    __shared__ float hm[128], ha[128];
    __shared__ float sc[2];
    const int b = blockIdx.x, t = threadIdx.x;
    for (int i = t; i < 512; i += 128) cs[i] = ctxv[b * 512 + i];
    __syncthreads();
    float hmv = mb1[t], hav = ab1[t];
    for (int c = 0; c < 512; ++c) {
        const float cv = cs[c];
        hmv = fmaf(cv, mw1[t * 512 + c], hmv);
        hav = fmaf(cv, aw1[t * 512 + c], hav);
    }
    {
        float s1 = waveSum(hmv);
        __syncthreads();
        if ((t & 63) == 0) sc[t >> 6] = s1;
        __syncthreads();
        const float mu = (sc[0] + sc[1]) * (1.0f / 128.0f);
        const float d = hmv - mu;
        float s2 = waveSum(d * d);
        __syncthreads();
        if ((t & 63) == 0) sc[t >> 6] = s2;
        __syncthreads();
        const float var = (sc[0] + sc[1]) * (1.0f / 128.0f);
        hm[t] = fmaxf(d / sqrtf(var + 1e-5f) * mlg[t] + mlb[t], 0.f);
    }
    {
        float s1 = waveSum(hav);
        __syncthreads();
        if ((t & 63) == 0) sc[t >> 6] = s1;
        __syncthreads();
        const float mu = (sc[0] + sc[1]) * (1.0f / 128.0f);
        const float d = hav - mu;
        float s2 = waveSum(d * d);
        __syncthreads();
        if ((t & 63) == 0) sc[t >> 6] = s2;
        __syncthreads();
        const float var = (sc[0] + sc[1]) * (1.0f / 128.0f);
        ha[t] = fmaxf(d / sqrtf(var + 1e-5f) * alg[t] + alb[t], 0.f);
    }
    __syncthreads();
    for (int o = t; o < 512; o += 128) {
        float sm = mb2[o], sa = ab2[o];
        for (int p = 0; p < 128; ++p) {
            sm = fmaf(hm[p], mw2[o * 128 + p], sm);
            sa = fmaf(ha[p], aw2[o * 128 + p], sa);
        }
        mulo[b * 512 + o] = 1.0f / (1.0f + __expf(-sm));
        addo[b * 512 + o] = sa;
    }
}

__global__ __launch_bounds__(256) void glob_ew_k(
    const u16* __restrict__ xb, const float* __restrict__ mulv,
    const float* __restrict__ addv, u16* __restrict__ g)
{
    const int idx = blockIdx.x * 256 + threadIdx.x;
    const int cq = idx & 63;
    const int n = (idx >> 6) % NPIX;
    const int b = (idx >> 6) / NPIX;
    const int c = cq * 8;
    const size_t base = ((size_t)b * NPIX + n) * NCH + c;
    ushort4 u0 = *reinterpret_cast<const ushort4*>(&xb[base]);
    ushort4 u1 = *reinterpret_cast<const ushort4*>(&xb[base + 4]);
    const float* mp = &mulv[b * NCH + c];
    const float* ap = &addv[b * NCH + c];
    float4 m0 = *reinterpret_cast<const float4*>(mp);
    float4 m1 = *reinterpret_cast<const float4*>(mp + 4);
    float4 a0 = *reinterpret_cast<const float4*>(ap);
    float4 a1 = *reinterpret_cast<const float4*>(ap + 4);
    ushort4 o0, o1;
    o0.x = f2bf(fmaf(bf2f(u0.x), m0.x, a0.x));
    o0.y = f2bf(fmaf(bf2f(u0.y), m0.y, a0.y));
    o0.z = f2bf(fmaf(bf2f(u0.z), m0.z, a0.z));
    o0.w = f2bf(fmaf(bf2f(u0.w), m0.w, a0.w));
    o1.x = f2bf(fmaf(bf2f(u1.x), m1.x, a1.x));
    o1.y = f2bf(fmaf(bf2f(u1.y), m1.y, a1.y));
    o1.z = f2bf(fmaf(bf2f(u1.z), m1.z, a1.z));
    o1.w = f2bf(fmaf(bf2f(u1.w), m1.w, a1.w));
    *reinterpret_cast<ushort4*>(&g[base]) = o0;
    *reinterpret_cast<ushort4*>(&g[base + 4]) = o1;
}

// ---------------- wave-per-row softmax + exact top-k ----------------
__global__ __launch_bounds__(256) void softmax_topk_wave(
    const u16* __restrict__ p, float* __restrict__ mxo,
    float* __restrict__ invSo, float* __restrict__ softo, int bOff)
{
    const int w = threadIdx.x >> 6, l = threadIdx.x & 63;
    const int r = blockIdx.x * 4 + w;
    const int bc = blockIdx.y;
    const u16* pr = p + ((size_t)bc * NPIX + r) * NPIX;
    float e[36];
    float mx = -3.4e38f;
    #pragma unroll
    for (int i = 0; i < 36; ++i) { e[i] = bf2f(pr[i * 64 + l]); mx = fmaxf(mx, e[i]); }
    #pragma unroll
    for (int o = 32; o > 0; o >>= 1) mx = fmaxf(mx, __shfl_xor(mx, o));
    float S = 0.f;
    #pragma unroll
    for (int i = 0; i < 36; ++i) { e[i] = __expf(e[i] - mx); S += e[i]; }
    #pragma unroll
    for (int o = 32; o > 0; o >>= 1) S += __shfl_xor(S, o);
    const float invS = 1.0f / S;
    unsigned lo = 0u, hi = 0x3F800000u;
    while (lo < hi) {
        const unsigned mid = lo + ((hi - lo + 1u) >> 1);
        const float tv = __uint_as_float(mid);
        int c = 0;
        #pragma unroll
        for (int i = 0; i < 36; ++i) c += (e[i] >= tv) ? 1 : 0;
        #pragma unroll
        for (int o = 32; o > 0; o >>= 1) c += __shfl_xor(c, o);
        if (c >= KNUM) lo = mid; else hi = mid - 1u;
    }
    const float tv = __uint_as_float(lo);
    float ss = 0.f; int a = 0;
    #pragma unroll
    for (int i = 0; i < 36; ++i) { if (e[i] > tv) { ss += e[i]; a++; } }
    #pragma unroll
    for (int o = 32; o > 0; o >>= 1) { ss += __shfl_xor(ss, o); a += __shfl_xor(a, o); }
    if (l == 0) {
        const size_t gi = (size_t)(bOff + bc) * NPIX + r;
        mxo[gi] = mx; invSo[gi] = invS;
        softo[gi] = (ss + (float)(KNUM - a) * tv) * invS * (1.0f / (float)KNUM);
    }
}

// colsum[b][j] = sum_i exp(p[i][j]-mx[i]) * invS[i]; i split 32 ways for occupancy.
__global__ __launch_bounds__(256) void colsum_k(
    const u16* __restrict__ p, const float* __restrict__ mxo,
    const float* __restrict__ invSo, float* __restrict__ colsum, int bOff)
{
    const int j = blockIdx.x * 256 + threadIdx.x;
    const int ic0 = blockIdx.y * 72;
    const int bc = blockIdx.z;
    const float* mxr = mxo + (size_t)(bOff + bc) * NPIX;
    const float* isr = invSo + (size_t)(bOff + bc) * NPIX;
    const u16* pb = p + (size_t)bc * NPIX * NPIX;
    float s = 0.f;
    #pragma unroll 4
    for (int i = ic0; i < ic0 + 72; ++i)
        s += __expf(bf2f(pb[(size_t)i * NPIX + j]) - mxr[i]) * isr[i];
    atomicAdd(&colsum[(size_t)(bOff + bc) * NPIX + j], s);
}

__global__ __launch_bounds__(512) void ctx2_pool_k(
    const u16* __restrict__ qkv, const float* __restrict__ colsum,
    const float* __restrict__ soft, float* __restrict__ ctx2)
{
    const int c = threadIdx.x, b = blockIdx.y;
    const int nn0 = blockIdx.x * 128;
    float s = 0.f;
    for (int n = nn0; n < nn0 + 128; ++n) {
        const float wgt = colsum[(size_t)b * NPIX + n] * soft[(size_t)b * NPIX + n];
        s = fmaf(bf2f(qkv[((size_t)b * NPIX + n) * 768 + 256 + c]), wgt, s);
    }
    atomicAdd(&ctx2[b * NCH + c], s * (1.0f / (float)NPIX));
}

__global__ __launch_bounds__(256) void compute_z(
    const float* __restrict__ finw, const float* __restrict__ ctx2, float* __restrict__ z)
{
    const int o = blockIdx.x * 256 + threadIdx.x;
    const int b = blockIdx.y;
    const float* c2 = ctx2 + b * NCH;
    const float* wr = finw + (size_t)o * 1024 + 512;
    float s = 0.f;
    for (int c = 0; c < NCH; ++c) s = fmaf(wr[c], c2[c], s);
    z[b * NCH + o] = s;
}

// ---------------- host launcher ----------------
extern "C" void kernel_launch(void* const* d_in, const int* in_sizes, int n_in,
                              void* d_out, int out_size, void* d_ws, size_t ws_size,
                              hipStream_t stream)
{
    (void)in_sizes; (void)n_in; (void)out_size; (void)ws_size;
    const float* x      = (const float*)d_in[0];
    const float* lb_w1  = (const float*)d_in[1];
    const float* lb_g1  = (const float*)d_in[2];
    const float* lb_b1  = (const float*)d_in[3];
    const float* lb_w2  = (const float*)d_in[4];
    const float* lb_g2  = (const float*)d_in[5];
    const float* lb_b2  = (const float*)d_in[6];
    const float* lb_w3  = (const float*)d_in[7];
    const float* lb_g3  = (const float*)d_in[8];
    const float* lb_b3  = (const float*)d_in[9];
    const float* cm_w   = (const float*)d_in[10];
    const float* cm_b   = (const float*)d_in[11];
    const float* ca_w1  = (const float*)d_in[12];
    const float* ca_b1  = (const float*)d_in[13];
    const float* ca_lg  = (const float*)d_in[14];
    const float* ca_lb  = (const float*)d_in[15];
    const float* ca_w2  = (const float*)d_in[16];
    const float* ca_b2  = (const float*)d_in[17];
    const float* cmu_w1 = (const float*)d_in[18];
    const float* cmu_b1 = (const float*)d_in[19];
    const float* cmu_lg = (const float*)d_in[20];
    const float* cmu_lb = (const float*)d_in[21];
    const float* cmu_w2 = (const float*)d_in[22];
    const float* cmu_b2 = (const float*)d_in[23];
    const float* fu_w   = (const float*)d_in[24];
    const float* fu_b   = (const float*)d_in[25];
    // 26..37 dead (region == 1 identically)
    const float* q_w    = (const float*)d_in[38];
    const float* k_w    = (const float*)d_in[39];
    const float* v_w    = (const float*)d_in[40];
    const float* fin_w  = (const float*)d_in[41];

    char* W = (char*)d_ws;
    const size_t SZ_ACT = (size_t)NB * NPIX * NCH * 2;     // 18,874,368 B
    u16* xb   = (u16*)(W);
    u16* bufA = (u16*)(W + SZ_ACT);                        // t1 -> local
    u16* bufB = (u16*)(W + 2 * SZ_ACT);                    // t2 -> glob
    u16* gx   = (u16*)(W + 3 * SZ_ACT);
    u16* qkv  = (u16*)(W + 4 * SZ_ACT);                    // [b][n][768]
    char* SM = W + 4 * SZ_ACT + (size_t)NB * NPIX * 768 * 2;
    float* logits = (float*)SM; SM += (size_t)NB * NPIX * 4;
    float* maskb  = (float*)SM; SM += (size_t)NB * NPIX * 4;
    float* mxb    = (float*)SM; SM += (size_t)NB * NPIX * 4;
    float* invSb  = (float*)SM; SM += (size_t)NB * NPIX * 4;
    float* softb  = (float*)SM; SM += (size_t)NB * NPIX * 4;
    float* colsum = (float*)SM; SM += (size_t)NB * NPIX * 4;  // zero region start
    float* ctxb   = (float*)SM; SM += (size_t)NB * NCH * 4;
    float* ctx2b  = (float*)SM; SM += (size_t)NB * NCH * 4;   // zero region end
    float* mulb   = (float*)SM; SM += (size_t)NB * NCH * 4;
    float* addb   = (float*)SM; SM += (size_t)NB * NCH * 4;
    float* zbuf   = (float*)SM; SM += (size_t)NB * NCH * 4;
    float* wfold  = (float*)SM; SM += (size_t)9 * NCH * 4;
    u16* w1b   = (u16*)SM; SM += (size_t)512 * 512 * 2;
    u16* w3b   = (u16*)SM; SM += (size_t)512 * 512 * 2;
    u16* fuwb  = (u16*)SM; SM += (size_t)512 * 1024 * 2;
    u16* finwb = (u16*)SM; SM += (size_t)512 * 1024 * 2;
    u16* qkvwb = (u16*)SM; SM += (size_t)768 * 512 * 2;
    u16* pbuf = xb;   // aliases pools 0-2 after they are dead (42.5MB < 56.6MB)

    const float invs  = 0.99999500003749978f;   // 1/sqrt(1+1e-5)
    const float rs128 = 0.08838834764831845f;   // 1/sqrt(128)
    const long SACT = (long)NPIX * NCH;

    // weight conversions
    cvt_bf16<<<256, 256, 0, stream>>>(lb_w1, w1b, 65536);
    cvt_bf16<<<256, 256, 0, stream>>>(lb_w3, w3b, 65536);
    cvt_bf16<<<512, 256, 0, stream>>>(fu_w, fuwb, 131072);
    cvt_bf16<<<512, 256, 0, stream>>>(fin_w, finwb, 131072);
    cvt_bf16<<<64, 256, 0, stream>>>(q_w, qkvwb, 16384);
    cvt_bf16<<<64, 256, 0, stream>>>(k_w, qkvwb + 128 * 512, 16384);
    cvt_bf16<<<256, 256, 0, stream>>>(v_w, qkvwb + 256 * 512, 65536);
    fold_dw<<<18, 256, 0, stream>>>(lb_w2, lb_g2, wfold);
    transpose_cvt<<<dim3(36, 8, 8), 256, 0, stream>>>(x, xb);
    hipMemsetAsync(colsum, 0, (size_t)NB * NPIX * 4 + 2 * (size_t)NB * NCH * 4, stream);

    // local branch
    mfma_gemm<<<dim3(18, 4, 8), 256, 0, stream>>>(w1b, 512, 0, xb, nullptr, 512, SACT,
        bufA, 512, SACT, lb_g1, lb_b1, nullptr, 0, 512, invs, 1);
    dwconv_k<<<9216, 256, 0, stream>>>(bufA, wfold, lb_b2, bufB);
    mfma_gemm<<<dim3(18, 4, 8), 256, 0, stream>>>(w3b, 512, 0, bufB, nullptr, 512, SACT,
        bufA, 512, SACT, lb_g3, lb_b3, nullptr, 0, 512, invs, 0);
    // ContextBlock
    mask_logits_k<<<dim3(576, 8), 256, 0, stream>>>(xb, cm_w, cm_b, logits);
    softmax_mask<<<8, 256, 0, stream>>>(logits, maskb);
    ctx_pool_k<<<dim3(18, 8), 512, 0, stream>>>(xb, maskb, ctxb);
    chan_mlps<<<8, 128, 0, stream>>>(ctxb,
        cmu_w1, cmu_b1, cmu_lg, cmu_lb, cmu_w2, cmu_b2,
        ca_w1, ca_b1, ca_lg, ca_lb, ca_w2, ca_b2, mulb, addb);
    glob_ew_k<<<4608, 256, 0, stream>>>(xb, mulb, addb, bufB);
    // fusion
    mfma_gemm<<<dim3(18, 4, 8), 256, 0, stream>>>(fuwb, 1024, 0, bufA, bufB, 512, SACT,
        gx, 512, SACT, nullptr, fu_b, nullptr, 0, 1024, 1.0f, 0);
    // q|k|v stacked projection
    mfma_gemm<<<dim3(18, 6, 8), 256, 0, stream>>>(qkvwb, 512, 0, gx, nullptr, 512, SACT,
        qkv, 768, (long)NPIX * 768, nullptr, nullptr, nullptr, 0, 512, 1.0f, 0);
    // attention in 2 chunks of 4 batches
    for (int cc = 0; cc < 2; ++cc) {
        const u16* kp = qkv + (size_t)cc * 4 * NPIX * 768 + 128;
        const u16* qp = qkv + (size_t)cc * 4 * NPIX * 768;
        mfma_gemm<<<dim3(18, 18, 4), 256, 0, stream>>>(kp, 768, (long)NPIX * 768,
            qp, nullptr, 768, (long)NPIX * 768,
            pbuf, NPIX, (long)NPIX * NPIX, nullptr, nullptr, nullptr, 0, 128, rs128, 0);
        softmax_topk_wave<<<dim3(576, 4), 256, 0, stream>>>(pbuf, mxb, invSb, softb, cc * 4);
        colsum_k<<<dim3(9, 32, 4), 256, 0, stream>>>(pbuf, mxb, invSb, colsum, cc * 4);
    }
    // epilogue path
    ctx2_pool_k<<<dim3(18, 8), 512, 0, stream>>>(qkv, colsum, softb, ctx2b);
    compute_z<<<dim3(2, 8), 256, 0, stream>>>(fin_w, ctx2b, zbuf);
    mfma_gemm<<<dim3(4, 18, 8), 256, 0, stream>>>(gx, 512, SACT, finwb, nullptr, 1024, 0,
        d_out, NPIX, (long)NCH * NPIX, nullptr, nullptr, zbuf, 512, 512, 1.0f, 2);
}

// Round 4
// 449.211 us; speedup vs baseline: 4.2085x; 1.0165x over previous
//
#include <hip/hip_runtime.h>
#include <math.h>

#define NPIX 2304
#define NCH  512
#define NB   8
#define KNUM 230

typedef unsigned short u16;
typedef __attribute__((ext_vector_type(8))) short short8v;
typedef __attribute__((ext_vector_type(4))) float float4v;

__device__ __forceinline__ float bf2f(u16 u) {
    union { unsigned v; float f; } x; x.v = ((unsigned)u) << 16; return x.f;
}
__device__ __forceinline__ u16 f2bf(float f) {
    union { float f; unsigned v; } x; x.f = f;
    unsigned r = x.v + 0x7FFFu + ((x.v >> 16) & 1u);   // RNE
    return (u16)(r >> 16);
}

// ---------------- reductions ----------------
__device__ __forceinline__ float waveSum(float v) {
    #pragma unroll
    for (int o = 32; o > 0; o >>= 1) v += __shfl_down(v, o);
    return v;
}
__device__ __forceinline__ float blockSum256(float v, float* sc4) {
    v = waveSum(v);
    __syncthreads();
    if ((threadIdx.x & 63) == 0) sc4[threadIdx.x >> 6] = v;
    __syncthreads();
    return sc4[0] + sc4[1] + sc4[2] + sc4[3];
}
__device__ __forceinline__ float waveMaxF(float v) {
    #pragma unroll
    for (int o = 32; o > 0; o >>= 1) v = fmaxf(v, __shfl_down(v, o));
    return v;
}
__device__ __forceinline__ float blockMax256(float v, float* sc4) {
    v = waveMaxF(v);
    __syncthreads();
    if ((threadIdx.x & 63) == 0) sc4[threadIdx.x >> 6] = v;
    __syncthreads();
    return fmaxf(fmaxf(sc4[0], sc4[1]), fmaxf(sc4[2], sc4[3]));
}

// ---------------- async global->LDS 16B ----------------
__device__ __forceinline__ void gl_lds16(const u16* g, u16* l) {
    __builtin_amdgcn_global_load_lds(
        reinterpret_cast<const unsigned __attribute__((address_space(1)))*>(
            reinterpret_cast<uintptr_t>(g)),
        reinterpret_cast<unsigned __attribute__((address_space(3)))*>(
            reinterpret_cast<uintptr_t>(l)),
        16, 0, 0);
}

// ---------------- bf16 MFMA GEMM ----------------
// D[R, Cl] = alpha*scaleR[R] * sum_k A[R,k]*B[Cl,k] + biasR[R] + biasC[b,Cl]
// A, B row-major, k contiguous. Output stored out[b][Cl][R] (R contiguous).
// flags: 1 = relu, 2 = fp32 output (else bf16).
// B1: second source for k >= 512 (channel concat).
__global__ __launch_bounds__(256, 2) void mfma_gemm(
    const u16* __restrict__ A, int ldA, long sA,
    const u16* __restrict__ B0, const u16* __restrict__ B1, int ldB, long sB,
    void* __restrict__ outp, int ldO, long sO,
    const float* __restrict__ scaleR, const float* __restrict__ biasR,
    const float* __restrict__ biasC, int ldbc,
    int K, float alpha, int flags)
{
    __shared__ u16 lA[128 * 64];
    __shared__ u16 lB[128 * 64];
    const int t  = threadIdx.x;
    const int w  = t >> 6, l = t & 63;
    const int wR = w >> 1, wC = w & 1;
    const int lg = l >> 4, lr = l & 15, l7 = l & 7;
    const int b   = blockIdx.z;
    const int Cl0 = blockIdx.x * 128;
    const int R0  = blockIdx.y * 128;
    const u16* Ab  = A + (size_t)b * sA;
    const u16* B0b = B0 + (size_t)b * sB;
    const u16* B1b = B1 ? B1 + (size_t)b * sB : nullptr;

    float4v acc[4][4];
    const float4v zero = {0.f, 0.f, 0.f, 0.f};
    #pragma unroll
    for (int i = 0; i < 4; ++i)
        #pragma unroll
        for (int j = 0; j < 4; ++j) acc[i][j] = zero;

    const int sr = t >> 3;     // staging row-in-issue (0..31)
    const int sp = t & 7;      // physical 16B chunk

    for (int k0 = 0; k0 < K; k0 += 64) {
        const u16* Bsrc = B0b; int kb = k0;
        if (B1b && k0 >= 512) { Bsrc = B1b; kb = k0 - 512; }
        #pragma unroll
        for (int i = 0; i < 4; ++i) {
            const int r  = i * 32 + sr;
            const int ca = sp ^ (r & 7);                  // pre-swizzled source chunk
            gl_lds16(Ab   + (size_t)(R0  + r) * ldA + (k0 + ca * 8), &lA[i * 2048 + t * 8]);
            gl_lds16(Bsrc + (size_t)(Cl0 + r) * ldB + (kb + ca * 8), &lB[i * 2048 + t * 8]);
        }
        __syncthreads();
        #pragma unroll
        for (int kk = 0; kk < 2; ++kk) {
            short8v af[4], bfv[4];
            const int p = (kk * 4 + lg) ^ l7;             // swizzled read chunk
            #pragma unroll
            for (int mt = 0; mt < 4; ++mt) {
                const int rA = wR * 64 + mt * 16 + lr;
                af[mt]  = *reinterpret_cast<const short8v*>(&lA[rA * 64 + p * 8]);
                const int rB = wC * 64 + mt * 16 + lr;
                bfv[mt] = *reinterpret_cast<const short8v*>(&lB[rB * 64 + p * 8]);
            }
            #pragma unroll
            for (int mt = 0; mt < 4; ++mt)
                #pragma unroll
                for (int nt = 0; nt < 4; ++nt)
                    acc[mt][nt] = __builtin_amdgcn_mfma_f32_16x16x32_bf16(
                        af[mt], bfv[nt], acc[mt][nt], 0, 0, 0);
        }
        __syncthreads();
    }

    const bool relu = (flags & 1), f32o = (flags & 2);
    #pragma unroll
    for (int nt = 0; nt < 4; ++nt) {
        const int Cl = Cl0 + wC * 64 + nt * 16 + lr;
        const float bc = biasC ? biasC[(size_t)b * ldbc + Cl] : 0.f;
        #pragma unroll
        for (int mt = 0; mt < 4; ++mt) {
            const int Rb = R0 + wR * 64 + mt * 16 + lg * 4;
            float4 scv = scaleR ? *reinterpret_cast<const float4*>(&scaleR[Rb])
                                : make_float4(1.f, 1.f, 1.f, 1.f);
            float4 bv  = biasR  ? *reinterpret_cast<const float4*>(&biasR[Rb])
                                : make_float4(0.f, 0.f, 0.f, 0.f);
            float vals[4];
            #pragma unroll
            for (int j = 0; j < 4; ++j) {
                const float sc = alpha * ((&scv.x)[j]);
                float v = acc[mt][nt][j] * sc + (&bv.x)[j] + bc;
                if (relu) v = fmaxf(v, 0.f);
                vals[j] = v;
            }
            if (f32o) {
                float* op = (float*)outp + (size_t)b * sO + (size_t)Cl * ldO + Rb;
                *reinterpret_cast<float4*>(op) = make_float4(vals[0], vals[1], vals[2], vals[3]);
            } else {
                ushort4 u;
                u.x = f2bf(vals[0]); u.y = f2bf(vals[1]);
                u.z = f2bf(vals[2]); u.w = f2bf(vals[3]);
                u16* op = (u16*)outp + (size_t)b * sO + (size_t)Cl * ldO + Rb;
                *reinterpret_cast<ushort4*>(op) = u;
            }
        }
    }
}

// ---------------- transpose+convert x: [b][c][n] f32 -> [b][n][c] bf16 ----------------
__global__ __launch_bounds__(256) void transpose_cvt(
    const float* __restrict__ x, u16* __restrict__ xb)
{
    __shared__ float tile[64][65];
    const int t = threadIdx.x;
    const int n0 = blockIdx.x * 64, c0 = blockIdx.y * 64, b = blockIdx.z;
    const int tr = t >> 4, tc4 = (t & 15) * 4;
    #pragma unroll
    for (int i = 0; i < 4; ++i) {
        const int cc = tr + i * 16;
        float4 v = *reinterpret_cast<const float4*>(
            x + ((size_t)(b * NCH + c0 + cc)) * NPIX + n0 + tc4);
        tile[cc][tc4 + 0] = v.x; tile[cc][tc4 + 1] = v.y;
        tile[cc][tc4 + 2] = v.z; tile[cc][tc4 + 3] = v.w;
    }
    __syncthreads();
    #pragma unroll
    for (int i = 0; i < 4; ++i) {
        const int nn = tr + i * 16;
        ushort4 u;
        u.x = f2bf(tile[tc4 + 0][nn]); u.y = f2bf(tile[tc4 + 1][nn]);
        u.z = f2bf(tile[tc4 + 2][nn]); u.w = f2bf(tile[tc4 + 3][nn]);
        *reinterpret_cast<ushort4*>(xb + ((size_t)b * NPIX + n0 + nn) * NCH + c0 + tc4) = u;
    }
}

// ---------------- f32 -> bf16 convert (n4 float4 groups) ----------------
__global__ __launch_bounds__(256) void cvt_bf16(
    const float* __restrict__ s, u16* __restrict__ d, int n4)
{
    const int i = blockIdx.x * 256 + threadIdx.x;
    if (i < n4) {
        float4 v = reinterpret_cast<const float4*>(s)[i];
        ushort4 u; u.x = f2bf(v.x); u.y = f2bf(v.y); u.z = f2bf(v.z); u.w = f2bf(v.w);
        reinterpret_cast<ushort4*>(d)[i] = u;
    }
}

// ---------------- fold BN scale into dw weights, tap-major ----------------
__global__ __launch_bounds__(256) void fold_dw(
    const float* __restrict__ wsrc, const float* __restrict__ g, float* __restrict__ wf)
{
    const int i = blockIdx.x * 256 + threadIdx.x;
    if (i < 9 * NCH) {
        const int c = i / 9, tap = i % 9;
        wf[tap * NCH + c] = wsrc[i] * g[c] * 0.99999500003749978f;
    }
}

// ---------------- depthwise 3x3 + BN + ReLU, [n][c] bf16 ----------------
__global__ __launch_bounds__(256) void dwconv_k(
    const u16* __restrict__ t1, const float* __restrict__ wf,
    const float* __restrict__ b2, u16* __restrict__ t2)
{
    const int idx = blockIdx.x * 256 + threadIdx.x;
    const int cq = idx & 127;
    const int n  = (idx >> 7) % NPIX;
    const int b  = (idx >> 7) / NPIX;
    const int c  = cq * 4;
    const int y = n / 48, x = n % 48;
    float s0 = 0.f, s1 = 0.f, s2 = 0.f, s3 = 0.f;
    #pragma unroll
    for (int dy = -1; dy <= 1; ++dy) {
        const int yy = y + dy;
        if (yy < 0 || yy >= 48) continue;
        #pragma unroll
        for (int dx = -1; dx <= 1; ++dx) {
            const int xx = x + dx;
            if (xx < 0 || xx >= 48) continue;
            ushort4 tv = *reinterpret_cast<const ushort4*>(
                &t1[((size_t)b * NPIX + yy * 48 + xx) * NCH + c]);
            float4 wv = *reinterpret_cast<const float4*>(
                &wf[((dy + 1) * 3 + dx + 1) * NCH + c]);
            s0 = fmaf(bf2f(tv.x), wv.x, s0); s1 = fmaf(bf2f(tv.y), wv.y, s1);
            s2 = fmaf(bf2f(tv.z), wv.z, s2); s3 = fmaf(bf2f(tv.w), wv.w, s3);
        }
    }
    float4 bb = *reinterpret_cast<const float4*>(&b2[c]);
    ushort4 o;
    o.x = f2bf(fmaxf(s0 + bb.x, 0.f)); o.y = f2bf(fmaxf(s1 + bb.y, 0.f));
    o.z = f2bf(fmaxf(s2 + bb.z, 0.f)); o.w = f2bf(fmaxf(s3 + bb.w, 0.f));
    *reinterpret_cast<ushort4*>(&t2[((size_t)b * NPIX + n) * NCH + c]) = o;
}

// ---------------- ContextBlock ----------------
__global__ __launch_bounds__(256) void mask_logits_k(
    const u16* __restrict__ xb, const float* __restrict__ cmw,
    const float* __restrict__ cmb, float* __restrict__ logits)
{
    const int w = threadIdx.x >> 6, l = threadIdx.x & 63;
    const int n = blockIdx.x * 4 + w, b = blockIdx.y;
    const ushort4* row = reinterpret_cast<const ushort4*>(xb + ((size_t)b * NPIX + n) * NCH);
    const int c0 = l * 8;
    ushort4 u0 = row[l * 2], u1 = row[l * 2 + 1];
    float4 w0 = *reinterpret_cast<const float4*>(&cmw[c0]);
    float4 w1 = *reinterpret_cast<const float4*>(&cmw[c0 + 4]);
    float s = bf2f(u0.x) * w0.x + bf2f(u0.y) * w0.y + bf2f(u0.z) * w0.z + bf2f(u0.w) * w0.w
            + bf2f(u1.x) * w1.x + bf2f(u1.y) * w1.y + bf2f(u1.z) * w1.z + bf2f(u1.w) * w1.w;
    s = waveSum(s);
    if (l == 0) logits[(size_t)b * NPIX + n] = s + cmb[0];
}

__global__ __launch_bounds__(256) void softmax_mask(
    const float* __restrict__ logits, float* __restrict__ mask)
{
    __shared__ float sc[4];
    const int b = blockIdx.x, t = threadIdx.x;
    const float* lr = logits + (size_t)b * NPIX;
    float mx = -3.4e38f;
    for (int i = t; i < NPIX; i += 256) mx = fmaxf(mx, lr[i]);
    mx = blockMax256(mx, sc);
    float s = 0.f;
    for (int i = t; i < NPIX; i += 256) s += __expf(lr[i] - mx);
    s = blockSum256(s, sc);
    const float inv = 1.0f / s;
    for (int i = t; i < NPIX; i += 256) mask[(size_t)b * NPIX + i] = __expf(lr[i] - mx) * inv;
}

__global__ __launch_bounds__(512) void ctx_pool_k(
    const u16* __restrict__ xb, const float* __restrict__ mask, float* __restrict__ ctx)
{
    const int c = threadIdx.x, b = blockIdx.y;
    const int nn0 = blockIdx.x * 128;
    float s = 0.f;
    for (int n = nn0; n < nn0 + 128; ++n)
        s = fmaf(bf2f(xb[((size_t)b * NPIX + n) * NCH + c]), mask[(size_t)b * NPIX + n], s);
    atomicAdd(&ctx[b * NCH + c], s);
}

__global__ __launch_bounds__(128) void chan_mlps(
    const float* __restrict__ ctxv,
    const float* __restrict__ mw1, const float* __restrict__ mb1,
    const float* __restrict__ mlg, const float* __restrict__ mlb,
    const float* __restrict__ mw2, const float* __restrict__ mb2,
    const float* __restrict__ aw1, const float* __restrict__ ab1,
    const float* __restrict__ alg, const float* __restrict__ alb,
    const float* __restrict__ aw2, const float* __restrict__ ab2,
    float* __restrict__ mulo, float* __restrict__ addo)
{
    __shared__ float cs[512];
    __shared__ float hm[128], ha[128];
    __shared__ float sc[2];
    const int b = blockIdx.x, t = threadIdx.x;
    for (int i = t; i < 512; i += 128) cs[i] = ctxv[b * 512 + i];
    __syncthreads();
    float hmv = mb1[t], hav = ab1[t];
    for (int c = 0; c < 512; ++c) {
        const float cv = cs[c];
        hmv = fmaf(cv, mw1[t * 512 + c], hmv);
        hav = fmaf(cv, aw1[t * 512 + c], hav);
    }
    {
        float s1 = waveSum(hmv);
        __syncthreads();
        if ((t & 63) == 0) sc[t >> 6] = s1;
        __syncthreads();
        const float mu = (sc[0] + sc[1]) * (1.0f / 128.0f);
        const float d = hmv - mu;
        float s2 = waveSum(d * d);
        __syncthreads();
        if ((t & 63) == 0) sc[t >> 6] = s2;
        __syncthreads();
        const float var = (sc[0] + sc[1]) * (1.0f / 128.0f);
        hm[t] = fmaxf(d / sqrtf(var + 1e-5f) * mlg[t] + mlb[t], 0.f);
    }
    {
        float s1 = waveSum(hav);
        __syncthreads();
        if ((t & 63) == 0) sc[t >> 6] = s1;
        __syncthreads();
        const float mu = (sc[0] + sc[1]) * (1.0f / 128.0f);
        const float d = hav - mu;
        float s2 = waveSum(d * d);
        __syncthreads();
        if ((t & 63) == 0) sc[t >> 6] = s2;
        __syncthreads();
        const float var = (sc[0] + sc[1]) * (1.0f / 128.0f);
        ha[t] = fmaxf(d / sqrtf(var + 1e-5f) * alg[t] + alb[t], 0.f);
    }
    __syncthreads();
    for (int o = t; o < 512; o += 128) {
        float sm = mb2[o], sa = ab2[o];
        for (int p = 0; p < 128; ++p) {
            sm = fmaf(hm[p], mw2[o * 128 + p], sm);
            sa = fmaf(ha[p], aw2[o * 128 + p], sa);
        }
        mulo[b * 512 + o] = 1.0f / (1.0f + __expf(-sm));
        addo[b * 512 + o] = sa;
    }
}

__global__ __launch_bounds__(256) void glob_ew_k(
    const u16* __restrict__ xb, const float* __restrict__ mulv,
    const float* __restrict__ addv, u16* __restrict__ g)
{
    const int idx = blockIdx.x * 256 + threadIdx.x;
    const int cq = idx & 63;
    const int n = (idx >> 6) % NPIX;
    const int b = (idx >> 6) / NPIX;
    const int c = cq * 8;
    const size_t base = ((size_t)b * NPIX + n) * NCH + c;
    ushort4 u0 = *reinterpret_cast<const ushort4*>(&xb[base]);
    ushort4 u1 = *reinterpret_cast<const ushort4*>(&xb[base + 4]);
    const float* mp = &mulv[b * NCH + c];
    const float* ap = &addv[b * NCH + c];
    float4 m0 = *reinterpret_cast<const float4*>(mp);
    float4 m1 = *reinterpret_cast<const float4*>(mp + 4);
    float4 a0 = *reinterpret_cast<const float4*>(ap);
    float4 a1 = *reinterpret_cast<const float4*>(ap + 4);
    ushort4 o0, o1;
    o0.x = f2bf(fmaf(bf2f(u0.x), m0.x, a0.x));
    o0.y = f2bf(fmaf(bf2f(u0.y), m0.y, a0.y));
    o0.z = f2bf(fmaf(bf2f(u0.z), m0.z, a0.z));
    o0.w = f2bf(fmaf(bf2f(u0.w), m0.w, a0.w));
    o1.x = f2bf(fmaf(bf2f(u1.x), m1.x, a1.x));
    o1.y = f2bf(fmaf(bf2f(u1.y), m1.y, a1.y));
    o1.z = f2bf(fmaf(bf2f(u1.z), m1.z, a1.z));
    o1.w = f2bf(fmaf(bf2f(u1.w), m1.w, a1.w));
    *reinterpret_cast<ushort4*>(&g[base]) = o0;
    *reinterpret_cast<ushort4*>(&g[base + 4]) = o1;
}

// ---------------- wave-per-row softmax + exact top-k (ballot counting) ----------------
__global__ __launch_bounds__(256) void softmax_topk_wave(
    const u16* __restrict__ p, float* __restrict__ mxo,
    float* __restrict__ invSo, float* __restrict__ softo, int bOff)
{
    const int w = threadIdx.x >> 6, l = threadIdx.x & 63;
    const int r = blockIdx.x * 4 + w;
    const int bc = blockIdx.y;
    const u16* pr = p + ((size_t)bc * NPIX + r) * NPIX;
    float e[36];
    float mx = -3.4e38f;
    #pragma unroll
    for (int i = 0; i < 36; ++i) { e[i] = bf2f(pr[i * 64 + l]); mx = fmaxf(mx, e[i]); }
    #pragma unroll
    for (int o = 32; o > 0; o >>= 1) mx = fmaxf(mx, __shfl_xor(mx, o));
    float S = 0.f;
    #pragma unroll
    for (int i = 0; i < 36; ++i) { e[i] = __expf(e[i] - mx); S += e[i]; }
    #pragma unroll
    for (int o = 32; o > 0; o >>= 1) S += __shfl_xor(S, o);
    const float invS = 1.0f / S;
    // exact k-th largest via bit-order binary search; counts via ballot+popc
    // (v_cmp -> 64-bit exec-mask, s_bcnt1 on SALU -> wave-uniform count, no shuffles)
    unsigned lo = 0u, hi = 0x3F800000u;
    while (lo < hi) {
        const unsigned mid = lo + ((hi - lo + 1u) >> 1);
        const float tv = __uint_as_float(mid);
        int c = 0;
        #pragma unroll
        for (int i = 0; i < 36; ++i)
            c += (int)__popcll(__ballot(e[i] >= tv));
        if (c >= KNUM) lo = mid; else hi = mid - 1u;
    }
    const float tv = __uint_as_float(lo);
    float ss = 0.f; int a = 0;
    #pragma unroll
    for (int i = 0; i < 36; ++i) {
        if (e[i] > tv) ss += e[i];
        a += (int)__popcll(__ballot(e[i] > tv));
    }
    #pragma unroll
    for (int o = 32; o > 0; o >>= 1) ss += __shfl_xor(ss, o);
    if (l == 0) {
        const size_t gi = (size_t)(bOff + bc) * NPIX + r;
        mxo[gi] = mx; invSo[gi] = invS;
        softo[gi] = (ss + (float)(KNUM - a) * tv) * invS * (1.0f / (float)KNUM);
    }
}

// colsum[b][j] = sum_i exp(p[i][j]-mx[i]) * invS[i]; i split 32 ways for occupancy.
__global__ __launch_bounds__(256) void colsum_k(
    const u16* __restrict__ p, const float* __restrict__ mxo,
    const float* __restrict__ invSo, float* __restrict__ colsum, int bOff)
{
    const int j = blockIdx.x * 256 + threadIdx.x;
    const int ic0 = blockIdx.y * 72;
    const int bc = blockIdx.z;
    const float* mxr = mxo + (size_t)(bOff + bc) * NPIX;
    const float* isr = invSo + (size_t)(bOff + bc) * NPIX;
    const u16* pb = p + (size_t)bc * NPIX * NPIX;
    float s = 0.f;
    #pragma unroll 4
    for (int i = ic0; i < ic0 + 72; ++i)
        s += __expf(bf2f(pb[(size_t)i * NPIX + j]) - mxr[i]) * isr[i];
    atomicAdd(&colsum[(size_t)(bOff + bc) * NPIX + j], s);
}

__global__ __launch_bounds__(512) void ctx2_pool_k(
    const u16* __restrict__ qkv, const float* __restrict__ colsum,
    const float* __restrict__ soft, float* __restrict__ ctx2)
{
    const int c = threadIdx.x, b = blockIdx.y;
    const int nn0 = blockIdx.x * 128;
    float s = 0.f;
    for (int n = nn0; n < nn0 + 128; ++n) {
        const float wgt = colsum[(size_t)b * NPIX + n] * soft[(size_t)b * NPIX + n];
        s = fmaf(bf2f(qkv[((size_t)b * NPIX + n) * 768 + 256 + c]), wgt, s);
    }
    atomicAdd(&ctx2[b * NCH + c], s * (1.0f / (float)NPIX));
}

__global__ __launch_bounds__(256) void compute_z(
    const float* __restrict__ finw, const float* __restrict__ ctx2, float* __restrict__ z)
{
    const int o = blockIdx.x * 256 + threadIdx.x;
    const int b = blockIdx.y;
    const float* c2 = ctx2 + b * NCH;
    const float* wr = finw + (size_t)o * 1024 + 512;
    float s = 0.f;
    for (int c = 0; c < NCH; ++c) s = fmaf(wr[c], c2[c], s);
    z[b * NCH + o] = s;
}

// ---------------- host launcher ----------------
extern "C" void kernel_launch(void* const* d_in, const int* in_sizes, int n_in,
                              void* d_out, int out_size, void* d_ws, size_t ws_size,
                              hipStream_t stream)
{
    (void)in_sizes; (void)n_in; (void)out_size; (void)ws_size;
    const float* x      = (const float*)d_in[0];
    const float* lb_w1  = (const float*)d_in[1];
    const float* lb_g1  = (const float*)d_in[2];
    const float* lb_b1  = (const float*)d_in[3];
    const float* lb_w2  = (const float*)d_in[4];
    const float* lb_g2  = (const float*)d_in[5];
    const float* lb_b2  = (const float*)d_in[6];
    const float* lb_w3  = (const float*)d_in[7];
    const float* lb_g3  = (const float*)d_in[8];
    const float* lb_b3  = (const float*)d_in[9];
    const float* cm_w   = (const float*)d_in[10];
    const float* cm_b   = (const float*)d_in[11];
    const float* ca_w1  = (const float*)d_in[12];
    const float* ca_b1  = (const float*)d_in[13];
    const float* ca_lg  = (const float*)d_in[14];
    const float* ca_lb  = (const float*)d_in[15];
    const float* ca_w2  = (const float*)d_in[16];
    const float* ca_b2  = (const float*)d_in[17];
    const float* cmu_w1 = (const float*)d_in[18];
    const float* cmu_b1 = (const float*)d_in[19];
    const float* cmu_lg = (const float*)d_in[20];
    const float* cmu_lb = (const float*)d_in[21];
    const float* cmu_w2 = (const float*)d_in[22];
    const float* cmu_b2 = (const float*)d_in[23];
    const float* fu_w   = (const float*)d_in[24];
    const float* fu_b   = (const float*)d_in[25];
    // 26..37 dead (region == 1 identically)
    const float* q_w    = (const float*)d_in[38];
    const float* k_w    = (const float*)d_in[39];
    const float* v_w    = (const float*)d_in[40];
    const float* fin_w  = (const float*)d_in[41];

    char* W = (char*)d_ws;
    const size_t SZ_ACT = (size_t)NB * NPIX * NCH * 2;     // 18,874,368 B
    u16* xb   = (u16*)(W);
    u16* bufA = (u16*)(W + SZ_ACT);                        // t1 -> local
    u16* bufB = (u16*)(W + 2 * SZ_ACT);                    // t2 -> glob
    u16* gx   = (u16*)(W + 3 * SZ_ACT);
    u16* qkv  = (u16*)(W + 4 * SZ_ACT);                    // [b][n][768]
    char* SM = W + 4 * SZ_ACT + (size_t)NB * NPIX * 768 * 2;
    float* logits = (float*)SM; SM += (size_t)NB * NPIX * 4;
    float* maskb  = (float*)SM; SM += (size_t)NB * NPIX * 4;
    float* mxb    = (float*)SM; SM += (size_t)NB * NPIX * 4;
    float* invSb  = (float*)SM; SM += (size_t)NB * NPIX * 4;
    float* softb  = (float*)SM; SM += (size_t)NB * NPIX * 4;
    float* colsum = (float*)SM; SM += (size_t)NB * NPIX * 4;  // zero region start
    float* ctxb   = (float*)SM; SM += (size_t)NB * NCH * 4;
    float* ctx2b  = (float*)SM; SM += (size_t)NB * NCH * 4;   // zero region end
    float* mulb   = (float*)SM; SM += (size_t)NB * NCH * 4;
    float* addb   = (float*)SM; SM += (size_t)NB * NCH * 4;
    float* zbuf   = (float*)SM; SM += (size_t)NB * NCH * 4;
    float* wfold  = (float*)SM; SM += (size_t)9 * NCH * 4;
    u16* w1b   = (u16*)SM; SM += (size_t)512 * 512 * 2;
    u16* w3b   = (u16*)SM; SM += (size_t)512 * 512 * 2;
    u16* fuwb  = (u16*)SM; SM += (size_t)512 * 1024 * 2;
    u16* finwb = (u16*)SM; SM += (size_t)512 * 1024 * 2;
    u16* qkvwb = (u16*)SM; SM += (size_t)768 * 512 * 2;
    u16* pbuf = xb;   // aliases pools 0-2 after they are dead (42.5MB < 56.6MB)

    const float invs  = 0.99999500003749978f;   // 1/sqrt(1+1e-5)
    const float rs128 = 0.08838834764831845f;   // 1/sqrt(128)
    const long SACT = (long)NPIX * NCH;

    // weight conversions
    cvt_bf16<<<256, 256, 0, stream>>>(lb_w1, w1b, 65536);
    cvt_bf16<<<256, 256, 0, stream>>>(lb_w3, w3b, 65536);
    cvt_bf16<<<512, 256, 0, stream>>>(fu_w, fuwb, 131072);
    cvt_bf16<<<512, 256, 0, stream>>>(fin_w, finwb, 131072);
    cvt_bf16<<<64, 256, 0, stream>>>(q_w, qkvwb, 16384);
    cvt_bf16<<<64, 256, 0, stream>>>(k_w, qkvwb + 128 * 512, 16384);
    cvt_bf16<<<256, 256, 0, stream>>>(v_w, qkvwb + 256 * 512, 65536);
    fold_dw<<<18, 256, 0, stream>>>(lb_w2, lb_g2, wfold);
    transpose_cvt<<<dim3(36, 8, 8), 256, 0, stream>>>(x, xb);
    hipMemsetAsync(colsum, 0, (size_t)NB * NPIX * 4 + 2 * (size_t)NB * NCH * 4, stream);

    // local branch
    mfma_gemm<<<dim3(18, 4, 8), 256, 0, stream>>>(w1b, 512, 0, xb, nullptr, 512, SACT,
        bufA, 512, SACT, lb_g1, lb_b1, nullptr, 0, 512, invs, 1);
    dwconv_k<<<9216, 256, 0, stream>>>(bufA, wfold, lb_b2, bufB);
    mfma_gemm<<<dim3(18, 4, 8), 256, 0, stream>>>(w3b, 512, 0, bufB, nullptr, 512, SACT,
        bufA, 512, SACT, lb_g3, lb_b3, nullptr, 0, 512, invs, 0);
    // ContextBlock
    mask_logits_k<<<dim3(576, 8), 256, 0, stream>>>(xb, cm_w, cm_b, logits);
    softmax_mask<<<8, 256, 0, stream>>>(logits, maskb);
    ctx_pool_k<<<dim3(18, 8), 512, 0, stream>>>(xb, maskb, ctxb);
    chan_mlps<<<8, 128, 0, stream>>>(ctxb,
        cmu_w1, cmu_b1, cmu_lg, cmu_lb, cmu_w2, cmu_b2,
        ca_w1, ca_b1, ca_lg, ca_lb, ca_w2, ca_b2, mulb, addb);
    glob_ew_k<<<4608, 256, 0, stream>>>(xb, mulb, addb, bufB);
    // fusion
    mfma_gemm<<<dim3(18, 4, 8), 256, 0, stream>>>(fuwb, 1024, 0, bufA, bufB, 512, SACT,
        gx, 512, SACT, nullptr, fu_b, nullptr, 0, 1024, 1.0f, 0);
    // q|k|v stacked projection
    mfma_gemm<<<dim3(18, 6, 8), 256, 0, stream>>>(qkvwb, 512, 0, gx, nullptr, 512, SACT,
        qkv, 768, (long)NPIX * 768, nullptr, nullptr, nullptr, 0, 512, 1.0f, 0);
    // attention in 2 chunks of 4 batches
    for (int cc = 0; cc < 2; ++cc) {
        const u16* kp = qkv + (size_t)cc * 4 * NPIX * 768 + 128;
        const u16* qp = qkv + (size_t)cc * 4 * NPIX * 768;
        mfma_gemm<<<dim3(18, 18, 4), 256, 0, stream>>>(kp, 768, (long)NPIX * 768,
            qp, nullptr, 768, (long)NPIX * 768,
            pbuf, NPIX, (long)NPIX * NPIX, nullptr, nullptr, nullptr, 0, 128, rs128, 0);
        softmax_topk_wave<<<dim3(576, 4), 256, 0, stream>>>(pbuf, mxb, invSb, softb, cc * 4);
        colsum_k<<<dim3(9, 32, 4), 256, 0, stream>>>(pbuf, mxb, invSb, colsum, cc * 4);
    }
    // epilogue path
    ctx2_pool_k<<<dim3(18, 8), 512, 0, stream>>>(qkv, colsum, softb, ctx2b);
    compute_z<<<dim3(2, 8), 256, 0, stream>>>(fin_w, ctx2b, zbuf);
    mfma_gemm<<<dim3(4, 18, 8), 256, 0, stream>>>(gx, 512, SACT, finwb, nullptr, 1024, 0,
        d_out, NPIX, (long)NCH * NPIX, nullptr, nullptr, zbuf, 512, 512, 1.0f, 2);
}

// Round 5
// 402.729 us; speedup vs baseline: 4.6942x; 1.1154x over previous
//
#include <hip/hip_runtime.h>
#include <math.h>

#define NPIX 2304
#define NCH  512
#define NB   8
#define KNUM 230

typedef unsigned short u16;
typedef __attribute__((ext_vector_type(8))) short short8v;
typedef __attribute__((ext_vector_type(4))) float float4v;

__device__ __forceinline__ float bf2f(u16 u) {
    union { unsigned v; float f; } x; x.v = ((unsigned)u) << 16; return x.f;
}
__device__ __forceinline__ u16 f2bf(float f) {
    union { float f; unsigned v; } x; x.f = f;
    unsigned r = x.v + 0x7FFFu + ((x.v >> 16) & 1u);   // RNE
    return (u16)(r >> 16);
}

// ---------------- reductions ----------------
__device__ __forceinline__ float waveSum(float v) {
    #pragma unroll
    for (int o = 32; o > 0; o >>= 1) v += __shfl_down(v, o);
    return v;
}
__device__ __forceinline__ float blockSum256(float v, float* sc4) {
    v = waveSum(v);
    __syncthreads();
    if ((threadIdx.x & 63) == 0) sc4[threadIdx.x >> 6] = v;
    __syncthreads();
    return sc4[0] + sc4[1] + sc4[2] + sc4[3];
}
__device__ __forceinline__ float waveMaxF(float v) {
    #pragma unroll
    for (int o = 32; o > 0; o >>= 1) v = fmaxf(v, __shfl_down(v, o));
    return v;
}
__device__ __forceinline__ float blockMax256(float v, float* sc4) {
    v = waveMaxF(v);
    __syncthreads();
    if ((threadIdx.x & 63) == 0) sc4[threadIdx.x >> 6] = v;
    __syncthreads();
    return fmaxf(fmaxf(sc4[0], sc4[1]), fmaxf(sc4[2], sc4[3]));
}

// ---------------- async global->LDS 16B ----------------
__device__ __forceinline__ void gl_lds16(const u16* g, u16* l) {
    __builtin_amdgcn_global_load_lds(
        reinterpret_cast<const unsigned __attribute__((address_space(1)))*>(
            reinterpret_cast<uintptr_t>(g)),
        reinterpret_cast<unsigned __attribute__((address_space(3)))*>(
            reinterpret_cast<uintptr_t>(l)),
        16, 0, 0);
}

// ---------------- bf16 MFMA GEMM ----------------
// D[R, Cl] = alpha*scaleR[R] * sum_k A[R,k]*B[Cl,k] + biasR[R] + biasC[b,Cl]
// A, B row-major, k contiguous. Output stored out[b][Cl][R] (R contiguous).
// flags: 1 = relu, 2 = fp32 output (else bf16).
// B1: second source for k >= 512 (channel concat).
__global__ __launch_bounds__(256, 2) void mfma_gemm(
    const u16* __restrict__ A, int ldA, long sA,
    const u16* __restrict__ B0, const u16* __restrict__ B1, int ldB, long sB,
    void* __restrict__ outp, int ldO, long sO,
    const float* __restrict__ scaleR, const float* __restrict__ biasR,
    const float* __restrict__ biasC, int ldbc,
    int K, float alpha, int flags)
{
    __shared__ u16 lA[128 * 64];
    __shared__ u16 lB[128 * 64];
    const int t  = threadIdx.x;
    const int w  = t >> 6, l = t & 63;
    const int wR = w >> 1, wC = w & 1;
    const int lg = l >> 4, lr = l & 15, l7 = l & 7;
    const int b   = blockIdx.z;
    const int Cl0 = blockIdx.x * 128;
    const int R0  = blockIdx.y * 128;
    const u16* Ab  = A + (size_t)b * sA;
    const u16* B0b = B0 + (size_t)b * sB;
    const u16* B1b = B1 ? B1 + (size_t)b * sB : nullptr;

    float4v acc[4][4];
    const float4v zero = {0.f, 0.f, 0.f, 0.f};
    #pragma unroll
    for (int i = 0; i < 4; ++i)
        #pragma unroll
        for (int j = 0; j < 4; ++j) acc[i][j] = zero;

    const int sr = t >> 3;     // staging row-in-issue (0..31)
    const int sp = t & 7;      // physical 16B chunk

    for (int k0 = 0; k0 < K; k0 += 64) {
        const u16* Bsrc = B0b; int kb = k0;
        if (B1b && k0 >= 512) { Bsrc = B1b; kb = k0 - 512; }
        #pragma unroll
        for (int i = 0; i < 4; ++i) {
            const int r  = i * 32 + sr;
            const int ca = sp ^ (r & 7);                  // pre-swizzled source chunk
            gl_lds16(Ab   + (size_t)(R0  + r) * ldA + (k0 + ca * 8), &lA[i * 2048 + t * 8]);
            gl_lds16(Bsrc + (size_t)(Cl0 + r) * ldB + (kb + ca * 8), &lB[i * 2048 + t * 8]);
        }
        __syncthreads();
        #pragma unroll
        for (int kk = 0; kk < 2; ++kk) {
            short8v af[4], bfv[4];
            const int p = (kk * 4 + lg) ^ l7;             // swizzled read chunk
            #pragma unroll
            for (int mt = 0; mt < 4; ++mt) {
                const int rA = wR * 64 + mt * 16 + lr;
                af[mt]  = *reinterpret_cast<const short8v*>(&lA[rA * 64 + p * 8]);
                const int rB = wC * 64 + mt * 16 + lr;
                bfv[mt] = *reinterpret_cast<const short8v*>(&lB[rB * 64 + p * 8]);
            }
            #pragma unroll
            for (int mt = 0; mt < 4; ++mt)
                #pragma unroll
                for (int nt = 0; nt < 4; ++nt)
                    acc[mt][nt] = __builtin_amdgcn_mfma_f32_16x16x32_bf16(
                        af[mt], bfv[nt], acc[mt][nt], 0, 0, 0);
        }
        __syncthreads();
    }

    const bool relu = (flags & 1), f32o = (flags & 2);
    #pragma unroll
    for (int nt = 0; nt < 4; ++nt) {
        const int Cl = Cl0 + wC * 64 + nt * 16 + lr;
        const float bc = biasC ? biasC[(size_t)b * ldbc + Cl] : 0.f;
        #pragma unroll
        for (int mt = 0; mt < 4; ++mt) {
            const int Rb = R0 + wR * 64 + mt * 16 + lg * 4;
            float4 scv = scaleR ? *reinterpret_cast<const float4*>(&scaleR[Rb])
                                : make_float4(1.f, 1.f, 1.f, 1.f);
            float4 bv  = biasR  ? *reinterpret_cast<const float4*>(&biasR[Rb])
                                : make_float4(0.f, 0.f, 0.f, 0.f);
            float vals[4];
            #pragma unroll
            for (int j = 0; j < 4; ++j) {
                const float sc = alpha * ((&scv.x)[j]);
                float v = acc[mt][nt][j] * sc + (&bv.x)[j] + bc;
                if (relu) v = fmaxf(v, 0.f);
                vals[j] = v;
            }
            if (f32o) {
                float* op = (float*)outp + (size_t)b * sO + (size_t)Cl * ldO + Rb;
                *reinterpret_cast<float4*>(op) = make_float4(vals[0], vals[1], vals[2], vals[3]);
            } else {
                ushort4 u;
                u.x = f2bf(vals[0]); u.y = f2bf(vals[1]);
                u.z = f2bf(vals[2]); u.w = f2bf(vals[3]);
                u16* op = (u16*)outp + (size_t)b * sO + (size_t)Cl * ldO + Rb;
                *reinterpret_cast<ushort4*>(op) = u;
            }
        }
    }
}

// ---------------- transpose+convert x: [b][c][n] f32 -> [b][n][c] bf16 ----------------
__global__ __launch_bounds__(256) void transpose_cvt(
    const float* __restrict__ x, u16* __restrict__ xb)
{
    __shared__ float tile[64][65];
    const int t = threadIdx.x;
    const int n0 = blockIdx.x * 64, c0 = blockIdx.y * 64, b = blockIdx.z;
    const int tr = t >> 4, tc4 = (t & 15) * 4;
    #pragma unroll
    for (int i = 0; i < 4; ++i) {
        const int cc = tr + i * 16;
        float4 v = *reinterpret_cast<const float4*>(
            x + ((size_t)(b * NCH + c0 + cc)) * NPIX + n0 + tc4);
        tile[cc][tc4 + 0] = v.x; tile[cc][tc4 + 1] = v.y;
        tile[cc][tc4 + 2] = v.z; tile[cc][tc4 + 3] = v.w;
    }
    __syncthreads();
    #pragma unroll
    for (int i = 0; i < 4; ++i) {
        const int nn = tr + i * 16;
        ushort4 u;
        u.x = f2bf(tile[tc4 + 0][nn]); u.y = f2bf(tile[tc4 + 1][nn]);
        u.z = f2bf(tile[tc4 + 2][nn]); u.w = f2bf(tile[tc4 + 3][nn]);
        *reinterpret_cast<ushort4*>(xb + ((size_t)b * NPIX + n0 + nn) * NCH + c0 + tc4) = u;
    }
}

// ---------------- f32 -> bf16 convert (n4 float4 groups) ----------------
__global__ __launch_bounds__(256) void cvt_bf16(
    const float* __restrict__ s, u16* __restrict__ d, int n4)
{
    const int i = blockIdx.x * 256 + threadIdx.x;
    if (i < n4) {
        float4 v = reinterpret_cast<const float4*>(s)[i];
        ushort4 u; u.x = f2bf(v.x); u.y = f2bf(v.y); u.z = f2bf(v.z); u.w = f2bf(v.w);
        reinterpret_cast<ushort4*>(d)[i] = u;
    }
}

// ---------------- fold BN scale into dw weights, tap-major ----------------
__global__ __launch_bounds__(256) void fold_dw(
    const float* __restrict__ wsrc, const float* __restrict__ g, float* __restrict__ wf)
{
    const int i = blockIdx.x * 256 + threadIdx.x;
    if (i < 9 * NCH) {
        const int c = i / 9, tap = i % 9;
        wf[tap * NCH + c] = wsrc[i] * g[c] * 0.99999500003749978f;
    }
}

// ---------------- depthwise 3x3 + BN + ReLU, [n][c] bf16 ----------------
__global__ __launch_bounds__(256) void dwconv_k(
    const u16* __restrict__ t1, const float* __restrict__ wf,
    const float* __restrict__ b2, u16* __restrict__ t2)
{
    const int idx = blockIdx.x * 256 + threadIdx.x;
    const int cq = idx & 127;
    const int n  = (idx >> 7) % NPIX;
    const int b  = (idx >> 7) / NPIX;
    const int c  = cq * 4;
    const int y = n / 48, x = n % 48;
    float s0 = 0.f, s1 = 0.f, s2 = 0.f, s3 = 0.f;
    #pragma unroll
    for (int dy = -1; dy <= 1; ++dy) {
        const int yy = y + dy;
        if (yy < 0 || yy >= 48) continue;
        #pragma unroll
        for (int dx = -1; dx <= 1; ++dx) {
            const int xx = x + dx;
            if (xx < 0 || xx >= 48) continue;
            ushort4 tv = *reinterpret_cast<const ushort4*>(
                &t1[((size_t)b * NPIX + yy * 48 + xx) * NCH + c]);
            float4 wv = *reinterpret_cast<const float4*>(
                &wf[((dy + 1) * 3 + dx + 1) * NCH + c]);
            s0 = fmaf(bf2f(tv.x), wv.x, s0); s1 = fmaf(bf2f(tv.y), wv.y, s1);
            s2 = fmaf(bf2f(tv.z), wv.z, s2); s3 = fmaf(bf2f(tv.w), wv.w, s3);
        }
    }
    float4 bb = *reinterpret_cast<const float4*>(&b2[c]);
    ushort4 o;
    o.x = f2bf(fmaxf(s0 + bb.x, 0.f)); o.y = f2bf(fmaxf(s1 + bb.y, 0.f));
    o.z = f2bf(fmaxf(s2 + bb.z, 0.f)); o.w = f2bf(fmaxf(s3 + bb.w, 0.f));
    *reinterpret_cast<ushort4*>(&t2[((size_t)b * NPIX + n) * NCH + c]) = o;
}

// ---------------- ContextBlock ----------------
__global__ __launch_bounds__(256) void mask_logits_k(
    const u16* __restrict__ xb, const float* __restrict__ cmw,
    const float* __restrict__ cmb, float* __restrict__ logits)
{
    const int w = threadIdx.x >> 6, l = threadIdx.x & 63;
    const int n = blockIdx.x * 4 + w, b = blockIdx.y;
    const ushort4* row = reinterpret_cast<const ushort4*>(xb + ((size_t)b * NPIX + n) * NCH);
    const int c0 = l * 8;
    ushort4 u0 = row[l * 2], u1 = row[l * 2 + 1];
    float4 w0 = *reinterpret_cast<const float4*>(&cmw[c0]);
    float4 w1 = *reinterpret_cast<const float4*>(&cmw[c0 + 4]);
    float s = bf2f(u0.x) * w0.x + bf2f(u0.y) * w0.y + bf2f(u0.z) * w0.z + bf2f(u0.w) * w0.w
            + bf2f(u1.x) * w1.x + bf2f(u1.y) * w1.y + bf2f(u1.z) * w1.z + bf2f(u1.w) * w1.w;
    s = waveSum(s);
    if (l == 0) logits[(size_t)b * NPIX + n] = s + cmb[0];
}

__global__ __launch_bounds__(256) void softmax_mask(
    const float* __restrict__ logits, float* __restrict__ mask)
{
    __shared__ float sc[4];
    const int b = blockIdx.x, t = threadIdx.x;
    const float* lr = logits + (size_t)b * NPIX;
    float mx = -3.4e38f;
    for (int i = t; i < NPIX; i += 256) mx = fmaxf(mx, lr[i]);
    mx = blockMax256(mx, sc);
    float s = 0.f;
    for (int i = t; i < NPIX; i += 256) s += __expf(lr[i] - mx);
    s = blockSum256(s, sc);
    const float inv = 1.0f / s;
    for (int i = t; i < NPIX; i += 256) mask[(size_t)b * NPIX + i] = __expf(lr[i] - mx) * inv;
}

__global__ __launch_bounds__(512) void ctx_pool_k(
    const u16* __restrict__ xb, const float* __restrict__ mask, float* __restrict__ ctx)
{
    const int c = threadIdx.x, b = blockIdx.y;
    const int nn0 = blockIdx.x * 128;
    float s = 0.f;
    for (int n = nn0; n < nn0 + 128; ++n)
        s = fmaf(bf2f(xb[((size_t)b * NPIX + n) * NCH + c]), mask[(size_t)b * NPIX + n], s);
    atomicAdd(&ctx[b * NCH + c], s);
}

// ---------------- channel MLPs v2: grid (path, batch), wave-cooperative GEMV ----------------
__global__ __launch_bounds__(256) void chan_mlp2(
    const float* __restrict__ ctxv,
    const float* __restrict__ mw1, const float* __restrict__ mb1,
    const float* __restrict__ mlg, const float* __restrict__ mlb,
    const float* __restrict__ mw2, const float* __restrict__ mb2,
    const float* __restrict__ aw1, const float* __restrict__ ab1,
    const float* __restrict__ alg, const float* __restrict__ alb,
    const float* __restrict__ aw2, const float* __restrict__ ab2,
    float* __restrict__ mulo, float* __restrict__ addo)
{
    __shared__ float cs[512];
    __shared__ float hn[128];
    __shared__ float sc4[4];
    const int path = blockIdx.x, b = blockIdx.y;
    const int t = threadIdx.x, w = t >> 6, l = t & 63;
    const float* W1 = path ? aw1 : mw1;
    const float* B1 = path ? ab1 : mb1;
    const float* LG = path ? alg : mlg;
    const float* LB = path ? alb : mlb;
    const float* W2 = path ? aw2 : mw2;
    const float* B2 = path ? ab2 : mb2;
    cs[t]       = ctxv[b * 512 + t];
    cs[t + 256] = ctxv[b * 512 + 256 + t];
    __syncthreads();
    // phase 1: each wave computes 32 hiddens; lane-split 512-dot, coalesced W1 rows
    const float4 ca = *reinterpret_cast<const float4*>(&cs[l * 8]);
    const float4 cb = *reinterpret_cast<const float4*>(&cs[l * 8 + 4]);
    #pragma unroll 4
    for (int hh = 0; hh < 32; ++hh) {
        const int h = w * 32 + hh;
        const float4 wa = *reinterpret_cast<const float4*>(&W1[h * 512 + l * 8]);
        const float4 wb = *reinterpret_cast<const float4*>(&W1[h * 512 + l * 8 + 4]);
        float s = wa.x * ca.x + wa.y * ca.y + wa.z * ca.z + wa.w * ca.w
                + wb.x * cb.x + wb.y * cb.y + wb.z * cb.z + wb.w * cb.w;
        s = waveSum(s);
        if (l == 0) hn[h] = s + B1[h];
    }
    __syncthreads();
    // LayerNorm over 128 + ReLU (threads >=128 contribute zeros)
    const float v = (t < 128) ? hn[t] : 0.f;
    const float s1 = blockSum256(v, sc4);
    const float mu = s1 * (1.0f / 128.0f);
    const float d = (t < 128) ? (v - mu) : 0.f;
    const float s2 = blockSum256(d * d, sc4);
    const float var = s2 * (1.0f / 128.0f);
    if (t < 128) hn[t] = fmaxf(d / sqrtf(var + 1e-5f) * LG[t] + LB[t], 0.f);
    __syncthreads();
    // phase 2: 512 outputs, 2 per thread, float4 W2 rows (L2-resident)
    #pragma unroll
    for (int oo = 0; oo < 2; ++oo) {
        const int o = t + oo * 256;
        float s = B2[o];
        #pragma unroll
        for (int p = 0; p < 128; p += 4) {
            const float4 wv = *reinterpret_cast<const float4*>(&W2[o * 128 + p]);
            s += wv.x * hn[p] + wv.y * hn[p + 1] + wv.z * hn[p + 2] + wv.w * hn[p + 3];
        }
        if (path == 0) mulo[b * 512 + o] = 1.0f / (1.0f + __expf(-s));
        else           addo[b * 512 + o] = s;
    }
}

__global__ __launch_bounds__(256) void glob_ew_k(
    const u16* __restrict__ xb, const float* __restrict__ mulv,
    const float* __restrict__ addv, u16* __restrict__ g)
{
    const int idx = blockIdx.x * 256 + threadIdx.x;
    const int cq = idx & 63;
    const int n = (idx >> 6) % NPIX;
    const int b = (idx >> 6) / NPIX;
    const int c = cq * 8;
    const size_t base = ((size_t)b * NPIX + n) * NCH + c;
    ushort4 u0 = *reinterpret_cast<const ushort4*>(&xb[base]);
    ushort4 u1 = *reinterpret_cast<const ushort4*>(&xb[base + 4]);
    const float* mp = &mulv[b * NCH + c];
    const float* ap = &addv[b * NCH + c];
    float4 m0 = *reinterpret_cast<const float4*>(mp);
    float4 m1 = *reinterpret_cast<const float4*>(mp + 4);
    float4 a0 = *reinterpret_cast<const float4*>(ap);
    float4 a1 = *reinterpret_cast<const float4*>(ap + 4);
    ushort4 o0, o1;
    o0.x = f2bf(fmaf(bf2f(u0.x), m0.x, a0.x));
    o0.y = f2bf(fmaf(bf2f(u0.y), m0.y, a0.y));
    o0.z = f2bf(fmaf(bf2f(u0.z), m0.z, a0.z));
    o0.w = f2bf(fmaf(bf2f(u0.w), m0.w, a0.w));
    o1.x = f2bf(fmaf(bf2f(u1.x), m1.x, a1.x));
    o1.y = f2bf(fmaf(bf2f(u1.y), m1.y, a1.y));
    o1.z = f2bf(fmaf(bf2f(u1.z), m1.z, a1.z));
    o1.w = f2bf(fmaf(bf2f(u1.w), m1.w, a1.w));
    *reinterpret_cast<ushort4*>(&g[base]) = o0;
    *reinterpret_cast<ushort4*>(&g[base + 4]) = o1;
}

// ---------------- wave-per-row softmax + exact top-k on bf16 keys ----------------
// All row statistics are permutation-invariant -> vector loads in any lane order.
// bf16 bits -> sortable u16 key; threshold search = 16-step MSB-first on key space.
__global__ __launch_bounds__(256) void softmax_topk_wave(
    const u16* __restrict__ p, float* __restrict__ mxo,
    float* __restrict__ invSo, float* __restrict__ softo, int bOff)
{
    const int w = threadIdx.x >> 6, l = threadIdx.x & 63;
    const int r = blockIdx.x * 4 + w;
    const int bc = blockIdx.y;
    const u16* pr = p + ((size_t)bc * NPIX + r) * NPIX;
    // coalesced: 4 x uint4 (1KB/instr per wave) + 1 x uint2 tail
    const uint4* p16 = reinterpret_cast<const uint4*>(pr);
    uint4 q0 = p16[l], q1 = p16[64 + l], q2 = p16[128 + l], q3 = p16[192 + l];
    uint2 q4 = reinterpret_cast<const uint2*>(pr)[512 + l];
    unsigned uw[18] = {q0.x, q0.y, q0.z, q0.w, q1.x, q1.y, q1.z, q1.w,
                       q2.x, q2.y, q2.z, q2.w, q3.x, q3.y, q3.z, q3.w,
                       q4.x, q4.y};
    unsigned km[36];
    #pragma unroll
    for (int i = 0; i < 18; ++i) {
        const unsigned v = uw[i];
        const unsigned m = ((v >> 15) & 0x10001u) * 0x7FFFu + 0x80008000u;
        const unsigned s = v ^ m;           // two sortable keys packed
        km[2 * i]     = s & 0xFFFFu;
        km[2 * i + 1] = s >> 16;
    }
    // wave max key -> row max value
    unsigned kmax = km[0];
    #pragma unroll
    for (int i = 1; i < 36; ++i) kmax = max(kmax, km[i]);
    #pragma unroll
    for (int o = 32; o > 0; o >>= 1) kmax = max(kmax, (unsigned)__shfl_xor((int)kmax, o));
    const unsigned mxbits = (kmax & 0x8000u) ? (kmax ^ 0x8000u) : (kmax ^ 0xFFFFu);
    const float mx = bf2f((u16)mxbits);
    // k-th largest key: MSB-first bit construction, counts via ballot+popc
    unsigned kt = 0u;
    for (int bit = 15; bit >= 0; --bit) {
        const unsigned cand = kt | (1u << bit);
        int c = 0;
        #pragma unroll
        for (int i = 0; i < 36; ++i)
            c += (int)__popcll(__ballot(km[i] >= cand));
        if (c >= KNUM) kt = cand;
    }
    const unsigned tbits = (kt & 0x8000u) ? (kt ^ 0x8000u) : (kt ^ 0xFFFFu);
    const float te = __expf(bf2f((u16)tbits) - mx);
    // single exp pass: S, top-sum ss, strict-count a
    float S = 0.f, ss = 0.f; int a = 0;
    #pragma unroll
    for (int i = 0; i < 36; ++i) {
        const unsigned bb = (km[i] & 0x8000u) ? (km[i] ^ 0x8000u) : (km[i] ^ 0xFFFFu);
        const float e = __expf(bf2f((u16)bb) - mx);
        S += e;
        const bool gt = km[i] > kt;
        if (gt) ss += e;
        a += (int)__popcll(__ballot(gt));
    }
    #pragma unroll
    for (int o = 32; o > 0; o >>= 1) { S += __shfl_xor(S, o); ss += __shfl_xor(ss, o); }
    if (l == 0) {
        const size_t gi = (size_t)(bOff + bc) * NPIX + r;
        mxo[gi] = mx; invSo[gi] = 1.0f / S;
        softo[gi] = (ss + (float)(KNUM - a) * te) / (S * (float)KNUM);
    }
}

// colsum[b][j] = sum_i exp(p[i][j]-mx[i]) * invS[i]; i split 32 ways for occupancy.
__global__ __launch_bounds__(256) void colsum_k(
    const u16* __restrict__ p, const float* __restrict__ mxo,
    const float* __restrict__ invSo, float* __restrict__ colsum, int bOff)
{
    const int j = blockIdx.x * 256 + threadIdx.x;
    const int ic0 = blockIdx.y * 72;
    const int bc = blockIdx.z;
    const float* mxr = mxo + (size_t)(bOff + bc) * NPIX;
    const float* isr = invSo + (size_t)(bOff + bc) * NPIX;
    const u16* pb = p + (size_t)bc * NPIX * NPIX;
    float s = 0.f;
    #pragma unroll 4
    for (int i = ic0; i < ic0 + 72; ++i)
        s += __expf(bf2f(pb[(size_t)i * NPIX + j]) - mxr[i]) * isr[i];
    atomicAdd(&colsum[(size_t)(bOff + bc) * NPIX + j], s);
}

__global__ __launch_bounds__(512) void ctx2_pool_k(
    const u16* __restrict__ qkv, const float* __restrict__ colsum,
    const float* __restrict__ soft, float* __restrict__ ctx2)
{
    const int c = threadIdx.x, b = blockIdx.y;
    const int nn0 = blockIdx.x * 128;
    float s = 0.f;
    for (int n = nn0; n < nn0 + 128; ++n) {
        const float wgt = colsum[(size_t)b * NPIX + n] * soft[(size_t)b * NPIX + n];
        s = fmaf(bf2f(qkv[((size_t)b * NPIX + n) * 768 + 256 + c]), wgt, s);
    }
    atomicAdd(&ctx2[b * NCH + c], s * (1.0f / (float)NPIX));
}

__global__ __launch_bounds__(256) void compute_z(
    const float* __restrict__ finw, const float* __restrict__ ctx2, float* __restrict__ z)
{
    const int o = blockIdx.x * 256 + threadIdx.x;
    const int b = blockIdx.y;
    const float* c2 = ctx2 + b * NCH;
    const float* wr = finw + (size_t)o * 1024 + 512;
    float s = 0.f;
    for (int c = 0; c < NCH; ++c) s = fmaf(wr[c], c2[c], s);
    z[b * NCH + o] = s;
}

// ---------------- host launcher ----------------
extern "C" void kernel_launch(void* const* d_in, const int* in_sizes, int n_in,
                              void* d_out, int out_size, void* d_ws, size_t ws_size,
                              hipStream_t stream)
{
    (void)in_sizes; (void)n_in; (void)out_size; (void)ws_size;
    const float* x      = (const float*)d_in[0];
    const float* lb_w1  = (const float*)d_in[1];
    const float* lb_g1  = (const float*)d_in[2];
    const float* lb_b1  = (const float*)d_in[3];
    const float* lb_w2  = (const float*)d_in[4];
    const float* lb_g2  = (const float*)d_in[5];
    const float* lb_b2  = (const float*)d_in[6];
    const float* lb_w3  = (const float*)d_in[7];
    const float* lb_g3  = (const float*)d_in[8];
    const float* lb_b3  = (const float*)d_in[9];
    const float* cm_w   = (const float*)d_in[10];
    const float* cm_b   = (const float*)d_in[11];
    const float* ca_w1  = (const float*)d_in[12];
    const float* ca_b1  = (const float*)d_in[13];
    const float* ca_lg  = (const float*)d_in[14];
    const float* ca_lb  = (const float*)d_in[15];
    const float* ca_w2  = (const float*)d_in[16];
    const float* ca_b2  = (const float*)d_in[17];
    const float* cmu_w1 = (const float*)d_in[18];
    const float* cmu_b1 = (const float*)d_in[19];
    const float* cmu_lg = (const float*)d_in[20];
    const float* cmu_lb = (const float*)d_in[21];
    const float* cmu_w2 = (const float*)d_in[22];
    const float* cmu_b2 = (const float*)d_in[23];
    const float* fu_w   = (const float*)d_in[24];
    const float* fu_b   = (const float*)d_in[25];
    // 26..37 dead (region == 1 identically)
    const float* q_w    = (const float*)d_in[38];
    const float* k_w    = (const float*)d_in[39];
    const float* v_w    = (const float*)d_in[40];
    const float* fin_w  = (const float*)d_in[41];

    char* W = (char*)d_ws;
    const size_t SZ_ACT = (size_t)NB * NPIX * NCH * 2;     // 18,874,368 B
    u16* xb   = (u16*)(W);
    u16* bufA = (u16*)(W + SZ_ACT);                        // t1 -> local
    u16* bufB = (u16*)(W + 2 * SZ_ACT);                    // t2 -> glob
    u16* gx   = (u16*)(W + 3 * SZ_ACT);
    u16* qkv  = (u16*)(W + 4 * SZ_ACT);                    // [b][n][768]
    char* SM = W + 4 * SZ_ACT + (size_t)NB * NPIX * 768 * 2;
    float* logits = (float*)SM; SM += (size_t)NB * NPIX * 4;
    float* maskb  = (float*)SM; SM += (size_t)NB * NPIX * 4;
    float* mxb    = (float*)SM; SM += (size_t)NB * NPIX * 4;
    float* invSb  = (float*)SM; SM += (size_t)NB * NPIX * 4;
    float* softb  = (float*)SM; SM += (size_t)NB * NPIX * 4;
    float* colsum = (float*)SM; SM += (size_t)NB * NPIX * 4;  // zero region start
    float* ctxb   = (float*)SM; SM += (size_t)NB * NCH * 4;
    float* ctx2b  = (float*)SM; SM += (size_t)NB * NCH * 4;   // zero region end
    float* mulb   = (float*)SM; SM += (size_t)NB * NCH * 4;
    float* addb   = (float*)SM; SM += (size_t)NB * NCH * 4;
    float* zbuf   = (float*)SM; SM += (size_t)NB * NCH * 4;
    float* wfold  = (float*)SM; SM += (size_t)9 * NCH * 4;
    u16* w1b   = (u16*)SM; SM += (size_t)512 * 512 * 2;
    u16* w3b   = (u16*)SM; SM += (size_t)512 * 512 * 2;
    u16* fuwb  = (u16*)SM; SM += (size_t)512 * 1024 * 2;
    u16* finwb = (u16*)SM; SM += (size_t)512 * 1024 * 2;
    u16* qkvwb = (u16*)SM; SM += (size_t)768 * 512 * 2;
    u16* pbuf = xb;   // aliases pools 0-2 after they are dead (42.5MB < 56.6MB)

    const float invs  = 0.99999500003749978f;   // 1/sqrt(1+1e-5)
    const float rs128 = 0.08838834764831845f;   // 1/sqrt(128)
    const long SACT = (long)NPIX * NCH;

    // weight conversions
    cvt_bf16<<<256, 256, 0, stream>>>(lb_w1, w1b, 65536);
    cvt_bf16<<<256, 256, 0, stream>>>(lb_w3, w3b, 65536);
    cvt_bf16<<<512, 256, 0, stream>>>(fu_w, fuwb, 131072);
    cvt_bf16<<<512, 256, 0, stream>>>(fin_w, finwb, 131072);
    cvt_bf16<<<64, 256, 0, stream>>>(q_w, qkvwb, 16384);
    cvt_bf16<<<64, 256, 0, stream>>>(k_w, qkvwb + 128 * 512, 16384);
    cvt_bf16<<<256, 256, 0, stream>>>(v_w, qkvwb + 256 * 512, 65536);
    fold_dw<<<18, 256, 0, stream>>>(lb_w2, lb_g2, wfold);
    transpose_cvt<<<dim3(36, 8, 8), 256, 0, stream>>>(x, xb);
    hipMemsetAsync(colsum, 0, (size_t)NB * NPIX * 4 + 2 * (size_t)NB * NCH * 4, stream);

    // local branch
    mfma_gemm<<<dim3(18, 4, 8), 256, 0, stream>>>(w1b, 512, 0, xb, nullptr, 512, SACT,
        bufA, 512, SACT, lb_g1, lb_b1, nullptr, 0, 512, invs, 1);
    dwconv_k<<<9216, 256, 0, stream>>>(bufA, wfold, lb_b2, bufB);
    mfma_gemm<<<dim3(18, 4, 8), 256, 0, stream>>>(w3b, 512, 0, bufB, nullptr, 512, SACT,
        bufA, 512, SACT, lb_g3, lb_b3, nullptr, 0, 512, invs, 0);
    // ContextBlock
    mask_logits_k<<<dim3(576, 8), 256, 0, stream>>>(xb, cm_w, cm_b, logits);
    softmax_mask<<<8, 256, 0, stream>>>(logits, maskb);
    ctx_pool_k<<<dim3(18, 8), 512, 0, stream>>>(xb, maskb, ctxb);
    chan_mlp2<<<dim3(2, 8), 256, 0, stream>>>(ctxb,
        cmu_w1, cmu_b1, cmu_lg, cmu_lb, cmu_w2, cmu_b2,
        ca_w1, ca_b1, ca_lg, ca_lb, ca_w2, ca_b2, mulb, addb);
    glob_ew_k<<<4608, 256, 0, stream>>>(xb, mulb, addb, bufB);
    // fusion
    mfma_gemm<<<dim3(18, 4, 8), 256, 0, stream>>>(fuwb, 1024, 0, bufA, bufB, 512, SACT,
        gx, 512, SACT, nullptr, fu_b, nullptr, 0, 1024, 1.0f, 0);
    // q|k|v stacked projection
    mfma_gemm<<<dim3(18, 6, 8), 256, 0, stream>>>(qkvwb, 512, 0, gx, nullptr, 512, SACT,
        qkv, 768, (long)NPIX * 768, nullptr, nullptr, nullptr, 0, 512, 1.0f, 0);
    // attention in 2 chunks of 4 batches
    for (int cc = 0; cc < 2; ++cc) {
        const u16* kp = qkv + (size_t)cc * 4 * NPIX * 768 + 128;
        const u16* qp = qkv + (size_t)cc * 4 * NPIX * 768;
        mfma_gemm<<<dim3(18, 18, 4), 256, 0, stream>>>(kp, 768, (long)NPIX * 768,
            qp, nullptr, 768, (long)NPIX * 768,
            pbuf, NPIX, (long)NPIX * NPIX, nullptr, nullptr, nullptr, 0, 128, rs128, 0);
        softmax_topk_wave<<<dim3(576, 4), 256, 0, stream>>>(pbuf, mxb, invSb, softb, cc * 4);
        colsum_k<<<dim3(9, 32, 4), 256, 0, stream>>>(pbuf, mxb, invSb, colsum, cc * 4);
    }
    // epilogue path
    ctx2_pool_k<<<dim3(18, 8), 512, 0, stream>>>(qkv, colsum, softb, ctx2b);
    compute_z<<<dim3(2, 8), 256, 0, stream>>>(fin_w, ctx2b, zbuf);
    mfma_gemm<<<dim3(4, 18, 8), 256, 0, stream>>>(gx, 512, SACT, finwb, nullptr, 1024, 0,
        d_out, NPIX, (long)NCH * NPIX, nullptr, nullptr, zbuf, 512, 512, 1.0f, 2);
}

// Round 6
// 382.150 us; speedup vs baseline: 4.9470x; 1.0538x over previous
//
#include <hip/hip_runtime.h>
#include <math.h>

#define NPIX 2304
#define NCH  512
#define NB   8
#define KNUM 230

typedef unsigned short u16;
typedef __attribute__((ext_vector_type(8))) short short8v;
typedef __attribute__((ext_vector_type(4))) float float4v;

__device__ __forceinline__ float bf2f(u16 u) {
    union { unsigned v; float f; } x; x.v = ((unsigned)u) << 16; return x.f;
}
__device__ __forceinline__ u16 f2bf(float f) {
    union { float f; unsigned v; } x; x.f = f;
    unsigned r = x.v + 0x7FFFu + ((x.v >> 16) & 1u);   // RNE
    return (u16)(r >> 16);
}

// ---------------- reductions ----------------
__device__ __forceinline__ float waveSum(float v) {
    #pragma unroll
    for (int o = 32; o > 0; o >>= 1) v += __shfl_down(v, o);
    return v;
}
__device__ __forceinline__ float blockSum256(float v, float* sc4) {
    v = waveSum(v);
    __syncthreads();
    if ((threadIdx.x & 63) == 0) sc4[threadIdx.x >> 6] = v;
    __syncthreads();
    return sc4[0] + sc4[1] + sc4[2] + sc4[3];
}
__device__ __forceinline__ float waveMaxF(float v) {
    #pragma unroll
    for (int o = 32; o > 0; o >>= 1) v = fmaxf(v, __shfl_down(v, o));
    return v;
}
__device__ __forceinline__ float blockMax256(float v, float* sc4) {
    v = waveMaxF(v);
    __syncthreads();
    if ((threadIdx.x & 63) == 0) sc4[threadIdx.x >> 6] = v;
    __syncthreads();
    return fmaxf(fmaxf(sc4[0], sc4[1]), fmaxf(sc4[2], sc4[3]));
}

// ---------------- async global->LDS 16B ----------------
__device__ __forceinline__ void gl_lds16(const u16* g, u16* l) {
    __builtin_amdgcn_global_load_lds(
        reinterpret_cast<const unsigned __attribute__((address_space(1)))*>(
            reinterpret_cast<uintptr_t>(g)),
        reinterpret_cast<unsigned __attribute__((address_space(3)))*>(
            reinterpret_cast<uintptr_t>(l)),
        16, 0, 0);
}

// ---------------- bf16 MFMA GEMM ----------------
// D[R, Cl] = alpha*scaleR[R] * sum_k A[R,k]*B[Cl,k] + biasR[R] + biasC[b,Cl]
// A, B row-major, k contiguous. Output stored out[b][Cl][R] (R contiguous).
// flags: 1 = relu, 2 = fp32 output (else bf16).
// B1: second source for k >= 512 (channel concat).
__global__ __launch_bounds__(256, 3) void mfma_gemm(
    const u16* __restrict__ A, int ldA, long sA,
    const u16* __restrict__ B0, const u16* __restrict__ B1, int ldB, long sB,
    void* __restrict__ outp, int ldO, long sO,
    const float* __restrict__ scaleR, const float* __restrict__ biasR,
    const float* __restrict__ biasC, int ldbc,
    int K, float alpha, int flags)
{
    __shared__ u16 lA[128 * 64];
    __shared__ u16 lB[128 * 64];
    const int t  = threadIdx.x;
    const int w  = t >> 6, l = t & 63;
    const int wR = w >> 1, wC = w & 1;
    const int lg = l >> 4, lr = l & 15, l7 = l & 7;
    const int b   = blockIdx.z;
    const int Cl0 = blockIdx.x * 128;
    const int R0  = blockIdx.y * 128;
    const u16* Ab  = A + (size_t)b * sA;
    const u16* B0b = B0 + (size_t)b * sB;
    const u16* B1b = B1 ? B1 + (size_t)b * sB : nullptr;

    float4v acc[4][4];
    const float4v zero = {0.f, 0.f, 0.f, 0.f};
    #pragma unroll
    for (int i = 0; i < 4; ++i)
        #pragma unroll
        for (int j = 0; j < 4; ++j) acc[i][j] = zero;

    const int sr = t >> 3;     // staging row-in-issue (0..31)
    const int sp = t & 7;      // physical 16B chunk

    for (int k0 = 0; k0 < K; k0 += 64) {
        const u16* Bsrc = B0b; int kb = k0;
        if (B1b && k0 >= 512) { Bsrc = B1b; kb = k0 - 512; }
        #pragma unroll
        for (int i = 0; i < 4; ++i) {
            const int r  = i * 32 + sr;
            const int ca = sp ^ (r & 7);                  // pre-swizzled source chunk
            gl_lds16(Ab   + (size_t)(R0  + r) * ldA + (k0 + ca * 8), &lA[i * 2048 + t * 8]);
            gl_lds16(Bsrc + (size_t)(Cl0 + r) * ldB + (kb + ca * 8), &lB[i * 2048 + t * 8]);
        }
        __syncthreads();
        #pragma unroll
        for (int kk = 0; kk < 2; ++kk) {
            short8v af[4], bfv[4];
            const int p = (kk * 4 + lg) ^ l7;             // swizzled read chunk
            #pragma unroll
            for (int mt = 0; mt < 4; ++mt) {
                const int rA = wR * 64 + mt * 16 + lr;
                af[mt]  = *reinterpret_cast<const short8v*>(&lA[rA * 64 + p * 8]);
                const int rB = wC * 64 + mt * 16 + lr;
                bfv[mt] = *reinterpret_cast<const short8v*>(&lB[rB * 64 + p * 8]);
            }
            #pragma unroll
            for (int mt = 0; mt < 4; ++mt)
                #pragma unroll
                for (int nt = 0; nt < 4; ++nt)
                    acc[mt][nt] = __builtin_amdgcn_mfma_f32_16x16x32_bf16(
                        af[mt], bfv[nt], acc[mt][nt], 0, 0, 0);
        }
        __syncthreads();
    }

    const bool relu = (flags & 1), f32o = (flags & 2);
    #pragma unroll
    for (int nt = 0; nt < 4; ++nt) {
        const int Cl = Cl0 + wC * 64 + nt * 16 + lr;
        const float bc = biasC ? biasC[(size_t)b * ldbc + Cl] : 0.f;
        #pragma unroll
        for (int mt = 0; mt < 4; ++mt) {
            const int Rb = R0 + wR * 64 + mt * 16 + lg * 4;
            float4 scv = scaleR ? *reinterpret_cast<const float4*>(&scaleR[Rb])
                                : make_float4(1.f, 1.f, 1.f, 1.f);
            float4 bv  = biasR  ? *reinterpret_cast<const float4*>(&biasR[Rb])
                                : make_float4(0.f, 0.f, 0.f, 0.f);
            float vals[4];
            #pragma unroll
            for (int j = 0; j < 4; ++j) {
                const float sc = alpha * ((&scv.x)[j]);
                float v = acc[mt][nt][j] * sc + (&bv.x)[j] + bc;
                if (relu) v = fmaxf(v, 0.f);
                vals[j] = v;
            }
            if (f32o) {
                float* op = (float*)outp + (size_t)b * sO + (size_t)Cl * ldO + Rb;
                *reinterpret_cast<float4*>(op) = make_float4(vals[0], vals[1], vals[2], vals[3]);
            } else {
                ushort4 u;
                u.x = f2bf(vals[0]); u.y = f2bf(vals[1]);
                u.z = f2bf(vals[2]); u.w = f2bf(vals[3]);
                u16* op = (u16*)outp + (size_t)b * sO + (size_t)Cl * ldO + Rb;
                *reinterpret_cast<ushort4*>(op) = u;
            }
        }
    }
}

// ---------------- transpose+convert x: [b][c][n] f32 -> [b][n][c] bf16 ----------------
__global__ __launch_bounds__(256) void transpose_cvt(
    const float* __restrict__ x, u16* __restrict__ xb)
{
    __shared__ float tile[64][65];
    const int t = threadIdx.x;
    const int n0 = blockIdx.x * 64, c0 = blockIdx.y * 64, b = blockIdx.z;
    const int tr = t >> 4, tc4 = (t & 15) * 4;
    #pragma unroll
    for (int i = 0; i < 4; ++i) {
        const int cc = tr + i * 16;
        float4 v = *reinterpret_cast<const float4*>(
            x + ((size_t)(b * NCH + c0 + cc)) * NPIX + n0 + tc4);
        tile[cc][tc4 + 0] = v.x; tile[cc][tc4 + 1] = v.y;
        tile[cc][tc4 + 2] = v.z; tile[cc][tc4 + 3] = v.w;
    }
    __syncthreads();
    #pragma unroll
    for (int i = 0; i < 4; ++i) {
        const int nn = tr + i * 16;
        ushort4 u;
        u.x = f2bf(tile[tc4 + 0][nn]); u.y = f2bf(tile[tc4 + 1][nn]);
        u.z = f2bf(tile[tc4 + 2][nn]); u.w = f2bf(tile[tc4 + 3][nn]);
        *reinterpret_cast<ushort4*>(xb + ((size_t)b * NPIX + n0 + nn) * NCH + c0 + tc4) = u;
    }
}

// ---------------- f32 -> bf16 convert (n4 float4 groups) ----------------
__global__ __launch_bounds__(256) void cvt_bf16(
    const float* __restrict__ s, u16* __restrict__ d, int n4)
{
    const int i = blockIdx.x * 256 + threadIdx.x;
    if (i < n4) {
        float4 v = reinterpret_cast<const float4*>(s)[i];
        ushort4 u; u.x = f2bf(v.x); u.y = f2bf(v.y); u.z = f2bf(v.z); u.w = f2bf(v.w);
        reinterpret_cast<ushort4*>(d)[i] = u;
    }
}

// ---------------- fold BN scale into dw weights, tap-major ----------------
__global__ __launch_bounds__(256) void fold_dw(
    const float* __restrict__ wsrc, const float* __restrict__ g, float* __restrict__ wf)
{
    const int i = blockIdx.x * 256 + threadIdx.x;
    if (i < 9 * NCH) {
        const int c = i / 9, tap = i % 9;
        wf[tap * NCH + c] = wsrc[i] * g[c] * 0.99999500003749978f;
    }
}

// ---------------- depthwise 3x3 + BN + ReLU, [n][c] bf16 ----------------
__global__ __launch_bounds__(256) void dwconv_k(
    const u16* __restrict__ t1, const float* __restrict__ wf,
    const float* __restrict__ b2, u16* __restrict__ t2)
{
    const int idx = blockIdx.x * 256 + threadIdx.x;
    const int cq = idx & 127;
    const int n  = (idx >> 7) % NPIX;
    const int b  = (idx >> 7) / NPIX;
    const int c  = cq * 4;
    const int y = n / 48, x = n % 48;
    float s0 = 0.f, s1 = 0.f, s2 = 0.f, s3 = 0.f;
    #pragma unroll
    for (int dy = -1; dy <= 1; ++dy) {
        const int yy = y + dy;
        if (yy < 0 || yy >= 48) continue;
        #pragma unroll
        for (int dx = -1; dx <= 1; ++dx) {
            const int xx = x + dx;
            if (xx < 0 || xx >= 48) continue;
            ushort4 tv = *reinterpret_cast<const ushort4*>(
                &t1[((size_t)b * NPIX + yy * 48 + xx) * NCH + c]);
            float4 wv = *reinterpret_cast<const float4*>(
                &wf[((dy + 1) * 3 + dx + 1) * NCH + c]);
            s0 = fmaf(bf2f(tv.x), wv.x, s0); s1 = fmaf(bf2f(tv.y), wv.y, s1);
            s2 = fmaf(bf2f(tv.z), wv.z, s2); s3 = fmaf(bf2f(tv.w), wv.w, s3);
        }
    }
    float4 bb = *reinterpret_cast<const float4*>(&b2[c]);
    ushort4 o;
    o.x = f2bf(fmaxf(s0 + bb.x, 0.f)); o.y = f2bf(fmaxf(s1 + bb.y, 0.f));
    o.z = f2bf(fmaxf(s2 + bb.z, 0.f)); o.w = f2bf(fmaxf(s3 + bb.w, 0.f));
    *reinterpret_cast<ushort4*>(&t2[((size_t)b * NPIX + n) * NCH + c]) = o;
}

// ---------------- ContextBlock ----------------
__global__ __launch_bounds__(256) void mask_logits_k(
    const u16* __restrict__ xb, const float* __restrict__ cmw,
    const float* __restrict__ cmb, float* __restrict__ logits)
{
    const int w = threadIdx.x >> 6, l = threadIdx.x & 63;
    const int n = blockIdx.x * 4 + w, b = blockIdx.y;
    const ushort4* row = reinterpret_cast<const ushort4*>(xb + ((size_t)b * NPIX + n) * NCH);
    const int c0 = l * 8;
    ushort4 u0 = row[l * 2], u1 = row[l * 2 + 1];
    float4 w0 = *reinterpret_cast<const float4*>(&cmw[c0]);
    float4 w1 = *reinterpret_cast<const float4*>(&cmw[c0 + 4]);
    float s = bf2f(u0.x) * w0.x + bf2f(u0.y) * w0.y + bf2f(u0.z) * w0.z + bf2f(u0.w) * w0.w
            + bf2f(u1.x) * w1.x + bf2f(u1.y) * w1.y + bf2f(u1.z) * w1.z + bf2f(u1.w) * w1.w;
    s = waveSum(s);
    if (l == 0) logits[(size_t)b * NPIX + n] = s + cmb[0];
}

__global__ __launch_bounds__(256) void softmax_mask(
    const float* __restrict__ logits, float* __restrict__ mask)
{
    __shared__ float sc[4];
    const int b = blockIdx.x, t = threadIdx.x;
    const float* lr = logits + (size_t)b * NPIX;
    float mx = -3.4e38f;
    for (int i = t; i < NPIX; i += 256) mx = fmaxf(mx, lr[i]);
    mx = blockMax256(mx, sc);
    float s = 0.f;
    for (int i = t; i < NPIX; i += 256) s += __expf(lr[i] - mx);
    s = blockSum256(s, sc);
    const float inv = 1.0f / s;
    for (int i = t; i < NPIX; i += 256) mask[(size_t)b * NPIX + i] = __expf(lr[i] - mx) * inv;
}

__global__ __launch_bounds__(512) void ctx_pool_k(
    const u16* __restrict__ xb, const float* __restrict__ mask, float* __restrict__ ctx)
{
    const int c = threadIdx.x, b = blockIdx.y;
    const int nn0 = blockIdx.x * 128;
    float s = 0.f;
    for (int n = nn0; n < nn0 + 128; ++n)
        s = fmaf(bf2f(xb[((size_t)b * NPIX + n) * NCH + c]), mask[(size_t)b * NPIX + n], s);
    atomicAdd(&ctx[b * NCH + c], s);
}

// ---------------- channel MLP v3: 3 stages, wave-per-dot parallelism ----------------
// stage 1: hnb[path][b][h] = B1[h] + dot(W1[h,:], ctx[b,:]); one wave per (path,h,b)
__global__ __launch_bounds__(256) void chan_h(
    const float* __restrict__ ctxv,
    const float* __restrict__ mw1, const float* __restrict__ mb1,
    const float* __restrict__ aw1, const float* __restrict__ ab1,
    float* __restrict__ hnb)
{
    const int w = threadIdx.x >> 6, l = threadIdx.x & 63;
    const int gid = blockIdx.x * 4 + w;          // 0..2047
    const int path = gid >> 10;
    const int rem  = gid & 1023;
    const int h = rem >> 3, b = rem & 7;
    const float* W1 = path ? aw1 : mw1;
    const float* B1 = path ? ab1 : mb1;
    const float4 wa = *reinterpret_cast<const float4*>(&W1[h * 512 + l * 8]);
    const float4 wb = *reinterpret_cast<const float4*>(&W1[h * 512 + l * 8 + 4]);
    const float4 ca = *reinterpret_cast<const float4*>(&ctxv[b * 512 + l * 8]);
    const float4 cb = *reinterpret_cast<const float4*>(&ctxv[b * 512 + l * 8 + 4]);
    float s = wa.x * ca.x + wa.y * ca.y + wa.z * ca.z + wa.w * ca.w
            + wb.x * cb.x + wb.y * cb.y + wb.z * cb.z + wb.w * cb.w;
    s = waveSum(s);
    if (l == 0) hnb[(path * 8 + b) * 128 + h] = s + B1[h];
}

// stage 2: LayerNorm(128) + ReLU in place
__global__ __launch_bounds__(128) void chan_ln(
    const float* __restrict__ mlg, const float* __restrict__ mlb,
    const float* __restrict__ alg, const float* __restrict__ alb,
    float* __restrict__ hnb)
{
    __shared__ float sc[2];
    const int path = blockIdx.x, b = blockIdx.y, t = threadIdx.x;
    float* hp = hnb + (path * 8 + b) * 128;
    const float v = hp[t];
    float s1 = waveSum(v);
    if ((t & 63) == 0) sc[t >> 6] = s1;
    __syncthreads();
    const float mu = (sc[0] + sc[1]) * (1.0f / 128.0f);
    const float d = v - mu;
    float s2 = waveSum(d * d);
    __syncthreads();
    if ((t & 63) == 0) sc[t >> 6] = s2;
    __syncthreads();
    const float var = (sc[0] + sc[1]) * (1.0f / 128.0f);
    const float* LG = path ? alg : mlg;
    const float* LB = path ? alb : mlb;
    hp[t] = fmaxf(d / sqrtf(var + 1e-5f) * LG[t] + LB[t], 0.f);
}

// stage 3: out[path][b][o] = W2[o,:] @ hn + B2[o]; sigmoid on mul path
__global__ __launch_bounds__(128) void chan_o(
    const float* __restrict__ hnb,
    const float* __restrict__ mw2, const float* __restrict__ mb2,
    const float* __restrict__ aw2, const float* __restrict__ ab2,
    float* __restrict__ mulo, float* __restrict__ addo)
{
    __shared__ float hs[128];
    const int oc = blockIdx.x, path = blockIdx.y, b = blockIdx.z;
    const int t = threadIdx.x;
    hs[t] = hnb[(path * 8 + b) * 128 + t];
    __syncthreads();
    const int o = oc * 128 + t;
    const float* W2 = path ? aw2 : mw2;
    float s = (path ? ab2 : mb2)[o];
    #pragma unroll
    for (int p = 0; p < 128; p += 4) {
        const float4 wv = *reinterpret_cast<const float4*>(&W2[o * 128 + p]);
        s += wv.x * hs[p] + wv.y * hs[p + 1] + wv.z * hs[p + 2] + wv.w * hs[p + 3];
    }
    if (path == 0) mulo[b * 512 + o] = 1.0f / (1.0f + __expf(-s));
    else           addo[b * 512 + o] = s;
}

__global__ __launch_bounds__(256) void glob_ew_k(
    const u16* __restrict__ xb, const float* __restrict__ mulv,
    const float* __restrict__ addv, u16* __restrict__ g)
{
    const int idx = blockIdx.x * 256 + threadIdx.x;
    const int cq = idx & 63;
    const int n = (idx >> 6) % NPIX;
    const int b = (idx >> 6) / NPIX;
    const int c = cq * 8;
    const size_t base = ((size_t)b * NPIX + n) * NCH + c;
    ushort4 u0 = *reinterpret_cast<const ushort4*>(&xb[base]);
    ushort4 u1 = *reinterpret_cast<const ushort4*>(&xb[base + 4]);
    const float* mp = &mulv[b * NCH + c];
    const float* ap = &addv[b * NCH + c];
    float4 m0 = *reinterpret_cast<const float4*>(mp);
    float4 m1 = *reinterpret_cast<const float4*>(mp + 4);
    float4 a0 = *reinterpret_cast<const float4*>(ap);
    float4 a1 = *reinterpret_cast<const float4*>(ap + 4);
    ushort4 o0, o1;
    o0.x = f2bf(fmaf(bf2f(u0.x), m0.x, a0.x));
    o0.y = f2bf(fmaf(bf2f(u0.y), m0.y, a0.y));
    o0.z = f2bf(fmaf(bf2f(u0.z), m0.z, a0.z));
    o0.w = f2bf(fmaf(bf2f(u0.w), m0.w, a0.w));
    o1.x = f2bf(fmaf(bf2f(u1.x), m1.x, a1.x));
    o1.y = f2bf(fmaf(bf2f(u1.y), m1.y, a1.y));
    o1.z = f2bf(fmaf(bf2f(u1.z), m1.z, a1.z));
    o1.w = f2bf(fmaf(bf2f(u1.w), m1.w, a1.w));
    *reinterpret_cast<ushort4*>(&g[base]) = o0;
    *reinterpret_cast<ushort4*>(&g[base + 4]) = o1;
}

// ---------------- wave-per-row softmax + exact top-k on bf16 keys ----------------
__global__ __launch_bounds__(256) void softmax_topk_wave(
    const u16* __restrict__ p, float* __restrict__ mxo,
    float* __restrict__ invSo, float* __restrict__ softo, int bOff)
{
    const int w = threadIdx.x >> 6, l = threadIdx.x & 63;
    const int r = blockIdx.x * 4 + w;
    const int bc = blockIdx.y;
    const u16* pr = p + ((size_t)bc * NPIX + r) * NPIX;
    const uint4* p16 = reinterpret_cast<const uint4*>(pr);
    uint4 q0 = p16[l], q1 = p16[64 + l], q2 = p16[128 + l], q3 = p16[192 + l];
    uint2 q4 = reinterpret_cast<const uint2*>(pr)[512 + l];
    unsigned uw[18] = {q0.x, q0.y, q0.z, q0.w, q1.x, q1.y, q1.z, q1.w,
                       q2.x, q2.y, q2.z, q2.w, q3.x, q3.y, q3.z, q3.w,
                       q4.x, q4.y};
    unsigned km[36];
    #pragma unroll
    for (int i = 0; i < 18; ++i) {
        const unsigned v = uw[i];
        const unsigned m = ((v >> 15) & 0x10001u) * 0x7FFFu + 0x80008000u;
        const unsigned s = v ^ m;           // two sortable keys packed
        km[2 * i]     = s & 0xFFFFu;
        km[2 * i + 1] = s >> 16;
    }
    unsigned kmax = km[0];
    #pragma unroll
    for (int i = 1; i < 36; ++i) kmax = max(kmax, km[i]);
    #pragma unroll
    for (int o = 32; o > 0; o >>= 1) kmax = max(kmax, (unsigned)__shfl_xor((int)kmax, o));
    const unsigned mxbits = (kmax & 0x8000u) ? (kmax ^ 0x8000u) : (kmax ^ 0xFFFFu);
    const float mx = bf2f((u16)mxbits);
    unsigned kt = 0u;
    for (int bit = 15; bit >= 0; --bit) {
        const unsigned cand = kt | (1u << bit);
        int c = 0;
        #pragma unroll
        for (int i = 0; i < 36; ++i)
            c += (int)__popcll(__ballot(km[i] >= cand));
        if (c >= KNUM) kt = cand;
    }
    const unsigned tbits = (kt & 0x8000u) ? (kt ^ 0x8000u) : (kt ^ 0xFFFFu);
    const float te = __expf(bf2f((u16)tbits) - mx);
    float S = 0.f, ss = 0.f; int a = 0;
    #pragma unroll
    for (int i = 0; i < 36; ++i) {
        const unsigned bb = (km[i] & 0x8000u) ? (km[i] ^ 0x8000u) : (km[i] ^ 0xFFFFu);
        const float e = __expf(bf2f((u16)bb) - mx);
        S += e;
        const bool gt = km[i] > kt;
        if (gt) ss += e;
        a += (int)__popcll(__ballot(gt));
    }
    #pragma unroll
    for (int o = 32; o > 0; o >>= 1) { S += __shfl_xor(S, o); ss += __shfl_xor(ss, o); }
    if (l == 0) {
        const size_t gi = (size_t)(bOff + bc) * NPIX + r;
        mxo[gi] = mx; invSo[gi] = 1.0f / S;
        softo[gi] = (ss + (float)(KNUM - a) * te) / (S * (float)KNUM);
    }
}

// colsum[b][j] = sum_i exp(p[i][j]-mx[i]) * invS[i]; i split 32 ways for occupancy.
__global__ __launch_bounds__(256) void colsum_k(
    const u16* __restrict__ p, const float* __restrict__ mxo,
    const float* __restrict__ invSo, float* __restrict__ colsum, int bOff)
{
    const int j = blockIdx.x * 256 + threadIdx.x;
    const int ic0 = blockIdx.y * 72;
    const int bc = blockIdx.z;
    const float* mxr = mxo + (size_t)(bOff + bc) * NPIX;
    const float* isr = invSo + (size_t)(bOff + bc) * NPIX;
    const u16* pb = p + (size_t)bc * NPIX * NPIX;
    float s = 0.f;
    #pragma unroll 4
    for (int i = ic0; i < ic0 + 72; ++i)
        s += __expf(bf2f(pb[(size_t)i * NPIX + j]) - mxr[i]) * isr[i];
    atomicAdd(&colsum[(size_t)(bOff + bc) * NPIX + j], s);
}

__global__ __launch_bounds__(512) void ctx2_pool_k(
    const u16* __restrict__ qkv, const float* __restrict__ colsum,
    const float* __restrict__ soft, float* __restrict__ ctx2)
{
    const int c = threadIdx.x, b = blockIdx.y;
    const int nn0 = blockIdx.x * 128;
    float s = 0.f;
    for (int n = nn0; n < nn0 + 128; ++n) {
        const float wgt = colsum[(size_t)b * NPIX + n] * soft[(size_t)b * NPIX + n];
        s = fmaf(bf2f(qkv[((size_t)b * NPIX + n) * 768 + 256 + c]), wgt, s);
    }
    atomicAdd(&ctx2[b * NCH + c], s * (1.0f / (float)NPIX));
}

__global__ __launch_bounds__(256) void compute_z(
    const float* __restrict__ finw, const float* __restrict__ ctx2, float* __restrict__ z)
{
    const int o = blockIdx.x * 256 + threadIdx.x;
    const int b = blockIdx.y;
    const float* c2 = ctx2 + b * NCH;
    const float* wr = finw + (size_t)o * 1024 + 512;
    float s = 0.f;
    for (int c = 0; c < NCH; ++c) s = fmaf(wr[c], c2[c], s);
    z[b * NCH + o] = s;
}

// ---------------- host launcher ----------------
extern "C" void kernel_launch(void* const* d_in, const int* in_sizes, int n_in,
                              void* d_out, int out_size, void* d_ws, size_t ws_size,
                              hipStream_t stream)
{
    (void)in_sizes; (void)n_in; (void)out_size; (void)ws_size;
    const float* x      = (const float*)d_in[0];
    const float* lb_w1  = (const float*)d_in[1];
    const float* lb_g1  = (const float*)d_in[2];
    const float* lb_b1  = (const float*)d_in[3];
    const float* lb_w2  = (const float*)d_in[4];
    const float* lb_g2  = (const float*)d_in[5];
    const float* lb_b2  = (const float*)d_in[6];
    const float* lb_w3  = (const float*)d_in[7];
    const float* lb_g3  = (const float*)d_in[8];
    const float* lb_b3  = (const float*)d_in[9];
    const float* cm_w   = (const float*)d_in[10];
    const float* cm_b   = (const float*)d_in[11];
    const float* ca_w1  = (const float*)d_in[12];
    const float* ca_b1  = (const float*)d_in[13];
    const float* ca_lg  = (const float*)d_in[14];
    const float* ca_lb  = (const float*)d_in[15];
    const float* ca_w2  = (const float*)d_in[16];
    const float* ca_b2  = (const float*)d_in[17];
    const float* cmu_w1 = (const float*)d_in[18];
    const float* cmu_b1 = (const float*)d_in[19];
    const float* cmu_lg = (const float*)d_in[20];
    const float* cmu_lb = (const float*)d_in[21];
    const float* cmu_w2 = (const float*)d_in[22];
    const float* cmu_b2 = (const float*)d_in[23];
    const float* fu_w   = (const float*)d_in[24];
    const float* fu_b   = (const float*)d_in[25];
    // 26..37 dead (region == 1 identically)
    const float* q_w    = (const float*)d_in[38];
    const float* k_w    = (const float*)d_in[39];
    const float* v_w    = (const float*)d_in[40];
    const float* fin_w  = (const float*)d_in[41];

    char* W = (char*)d_ws;
    const size_t SZ_ACT = (size_t)NB * NPIX * NCH * 2;     // 18,874,368 B
    u16* xb   = (u16*)(W);
    u16* bufA = (u16*)(W + SZ_ACT);                        // t1 -> local
    u16* bufB = (u16*)(W + 2 * SZ_ACT);                    // t2 -> glob
    u16* gx   = (u16*)(W + 3 * SZ_ACT);
    u16* qkv  = (u16*)(W + 4 * SZ_ACT);                    // [b][n][768]
    char* SM = W + 4 * SZ_ACT + (size_t)NB * NPIX * 768 * 2;
    float* logits = (float*)SM; SM += (size_t)NB * NPIX * 4;
    float* maskb  = (float*)SM; SM += (size_t)NB * NPIX * 4;
    float* mxb    = (float*)SM; SM += (size_t)NB * NPIX * 4;
    float* invSb  = (float*)SM; SM += (size_t)NB * NPIX * 4;
    float* softb  = (float*)SM; SM += (size_t)NB * NPIX * 4;
    float* colsum = (float*)SM; SM += (size_t)NB * NPIX * 4;  // zero region start
    float* ctxb   = (float*)SM; SM += (size_t)NB * NCH * 4;
    float* ctx2b  = (float*)SM; SM += (size_t)NB * NCH * 4;   // zero region end
    float* mulb   = (float*)SM; SM += (size_t)NB * NCH * 4;
    float* addb   = (float*)SM; SM += (size_t)NB * NCH * 4;
    float* zbuf   = (float*)SM; SM += (size_t)NB * NCH * 4;
    float* hnb    = (float*)SM; SM += (size_t)2 * NB * 128 * 4;
    float* wfold  = (float*)SM; SM += (size_t)9 * NCH * 4;
    u16* w1b   = (u16*)SM; SM += (size_t)512 * 512 * 2;
    u16* w3b   = (u16*)SM; SM += (size_t)512 * 512 * 2;
    u16* fuwb  = (u16*)SM; SM += (size_t)512 * 1024 * 2;
    u16* finwb = (u16*)SM; SM += (size_t)512 * 1024 * 2;
    u16* qkvwb = (u16*)SM; SM += (size_t)768 * 512 * 2;
    u16* pbuf = xb;   // aliases pools 0-2 after they are dead (42.5MB < 56.6MB)

    const float invs  = 0.99999500003749978f;   // 1/sqrt(1+1e-5)
    const float rs128 = 0.08838834764831845f;   // 1/sqrt(128)
    const long SACT = (long)NPIX * NCH;

    // weight conversions
    cvt_bf16<<<256, 256, 0, stream>>>(lb_w1, w1b, 65536);
    cvt_bf16<<<256, 256, 0, stream>>>(lb_w3, w3b, 65536);
    cvt_bf16<<<512, 256, 0, stream>>>(fu_w, fuwb, 131072);
    cvt_bf16<<<512, 256, 0, stream>>>(fin_w, finwb, 131072);
    cvt_bf16<<<64, 256, 0, stream>>>(q_w, qkvwb, 16384);
    cvt_bf16<<<64, 256, 0, stream>>>(k_w, qkvwb + 128 * 512, 16384);
    cvt_bf16<<<256, 256, 0, stream>>>(v_w, qkvwb + 256 * 512, 65536);
    fold_dw<<<18, 256, 0, stream>>>(lb_w2, lb_g2, wfold);
    transpose_cvt<<<dim3(36, 8, 8), 256, 0, stream>>>(x, xb);
    hipMemsetAsync(colsum, 0, (size_t)NB * NPIX * 4 + 2 * (size_t)NB * NCH * 4, stream);

    // local branch
    mfma_gemm<<<dim3(18, 4, 8), 256, 0, stream>>>(w1b, 512, 0, xb, nullptr, 512, SACT,
        bufA, 512, SACT, lb_g1, lb_b1, nullptr, 0, 512, invs, 1);
    dwconv_k<<<9216, 256, 0, stream>>>(bufA, wfold, lb_b2, bufB);
    mfma_gemm<<<dim3(18, 4, 8), 256, 0, stream>>>(w3b, 512, 0, bufB, nullptr, 512, SACT,
        bufA, 512, SACT, lb_g3, lb_b3, nullptr, 0, 512, invs, 0);
    // ContextBlock
    mask_logits_k<<<dim3(576, 8), 256, 0, stream>>>(xb, cm_w, cm_b, logits);
    softmax_mask<<<8, 256, 0, stream>>>(logits, maskb);
    ctx_pool_k<<<dim3(18, 8), 512, 0, stream>>>(xb, maskb, ctxb);
    chan_h<<<512, 256, 0, stream>>>(ctxb, cmu_w1, cmu_b1, ca_w1, ca_b1, hnb);
    chan_ln<<<dim3(2, 8), 128, 0, stream>>>(cmu_lg, cmu_lb, ca_lg, ca_lb, hnb);
    chan_o<<<dim3(4, 2, 8), 128, 0, stream>>>(hnb, cmu_w2, cmu_b2, ca_w2, ca_b2, mulb, addb);
    glob_ew_k<<<4608, 256, 0, stream>>>(xb, mulb, addb, bufB);
    // fusion
    mfma_gemm<<<dim3(18, 4, 8), 256, 0, stream>>>(fuwb, 1024, 0, bufA, bufB, 512, SACT,
        gx, 512, SACT, nullptr, fu_b, nullptr, 0, 1024, 1.0f, 0);
    // q|k|v stacked projection
    mfma_gemm<<<dim3(18, 6, 8), 256, 0, stream>>>(qkvwb, 512, 0, gx, nullptr, 512, SACT,
        qkv, 768, (long)NPIX * 768, nullptr, nullptr, nullptr, 0, 512, 1.0f, 0);
    // attention in 2 chunks of 4 batches
    for (int cc = 0; cc < 2; ++cc) {
        const u16* kp = qkv + (size_t)cc * 4 * NPIX * 768 + 128;
        const u16* qp = qkv + (size_t)cc * 4 * NPIX * 768;
        mfma_gemm<<<dim3(18, 18, 4), 256, 0, stream>>>(kp, 768, (long)NPIX * 768,
            qp, nullptr, 768, (long)NPIX * 768,
            pbuf, NPIX, (long)NPIX * NPIX, nullptr, nullptr, nullptr, 0, 128, rs128, 0);
        softmax_topk_wave<<<dim3(576, 4), 256, 0, stream>>>(pbuf, mxb, invSb, softb, cc * 4);
        colsum_k<<<dim3(9, 32, 4), 256, 0, stream>>>(pbuf, mxb, invSb, colsum, cc * 4);
    }
    // epilogue path
    ctx2_pool_k<<<dim3(18, 8), 512, 0, stream>>>(qkv, colsum, softb, ctx2b);
    compute_z<<<dim3(2, 8), 256, 0, stream>>>(fin_w, ctx2b, zbuf);
    mfma_gemm<<<dim3(4, 18, 8), 256, 0, stream>>>(gx, 512, SACT, finwb, nullptr, 1024, 0,
        d_out, NPIX, (long)NCH * NPIX, nullptr, nullptr, zbuf, 512, 512, 1.0f, 2);
}